// Round 1
// baseline (1767.670 us; speedup 1.0000x reference)
//
#include <hip/hip_runtime.h>
#include <math.h>

#define D    128
#define QN   4
#define CN   4
#define MAXC 4
#define BB   128
#define SS   64
#define RK   10
#define T    384   // 6 waves

// transposed-weight workspace layout (floats)
#define SZ_IH1  (256*384)
#define SZ_HH1  (128*384)
#define SZ_SQ   (128*128)
#define OFF_IH1  0
#define OFF_HH1  (OFF_IH1 + SZ_IH1)
#define OFF_IH2  (OFF_HH1 + SZ_HH1)
#define OFF_HH2  (OFF_IH2 + SZ_HH1)
#define OFF_AGG0 (OFF_HH2 + SZ_HH1)
#define OFF_AGG1 (OFF_AGG0 + SZ_SQ)
#define OFF_LAST (OFF_AGG1 + SZ_SQ)
#define OFF_QRY  (OFF_LAST + SZ_SQ)
#define WS_FLOATS (OFF_QRY + SZ_SQ)

__global__ void gikt_transpose(const float* __restrict__ Wih1,
                               const float* __restrict__ Whh1,
                               const float* __restrict__ Wih2,
                               const float* __restrict__ Whh2,
                               const float* __restrict__ Wagg,
                               const float* __restrict__ Wlast,
                               const float* __restrict__ Wqry,
                               float* __restrict__ ws)
{
  int i = blockIdx.x * blockDim.x + threadIdx.x;
  if (i >= WS_FLOATS) return;
  int j = i;
  if (j < SZ_IH1) { int e = j / 384, r = j - e*384; ws[i] = Wih1[r*256 + e]; return; }
  j -= SZ_IH1;
  if (j < SZ_HH1) { int e = j / 384, r = j - e*384; ws[i] = Whh1[r*128 + e]; return; }
  j -= SZ_HH1;
  if (j < SZ_HH1) { int e = j / 384, r = j - e*384; ws[i] = Wih2[r*128 + e]; return; }
  j -= SZ_HH1;
  if (j < SZ_HH1) { int e = j / 384, r = j - e*384; ws[i] = Whh2[r*128 + e]; return; }
  j -= SZ_HH1;
  if (j < SZ_SQ)  { int e = j >> 7, r = j & 127; ws[i] = Wagg[r*128 + e]; return; }
  j -= SZ_SQ;
  if (j < SZ_SQ)  { int e = j >> 7, r = j & 127; ws[i] = Wagg[128*128 + r*128 + e]; return; }
  j -= SZ_SQ;
  if (j < SZ_SQ)  { int e = j >> 7, r = j & 127; ws[i] = Wlast[r*128 + e]; return; }
  j -= SZ_SQ;
  { int e = j >> 7, r = j & 127; ws[i] = Wqry[r*128 + e]; }
}

__launch_bounds__(T, 1)
__global__ void gikt_main(
    const float* __restrict__ embQ,
    const float* __restrict__ embC,
    const float* __restrict__ embR,
    const float* __restrict__ b_ih1,
    const float* __restrict__ b_hh1,
    const float* __restrict__ b_ih2,
    const float* __restrict__ b_hh2,
    const float* __restrict__ b_agg,
    const float* __restrict__ b_last,
    const float* __restrict__ b_query,
    const float* __restrict__ w_k,
    const float* __restrict__ h1i,
    const float* __restrict__ h2i,
    const int* __restrict__ qnbr,
    const int* __restrict__ cnbr,
    const int* __restrict__ q2c,
    const int* __restrict__ qseq,
    const int* __restrict__ cseq,
    const int* __restrict__ mseq,
    const float* __restrict__ ws,
    float* __restrict__ y)
{
  const int b   = blockIdx.x;
  const int tid = threadIdx.x;

  const float* WT_ih1 = ws + OFF_IH1;  // [256][384]
  const float* WT_hh1 = ws + OFF_HH1;  // [128][384]
  const float* WT_ih2 = ws + OFF_IH2;  // [128][384]
  const float* WT_hh2 = ws + OFF_HH2;  // [128][384]
  const float* WT_a0  = ws + OFF_AGG0; // [128][128]
  const float* WT_a1  = ws + OFF_AGG1;
  const float* WT_ls  = ws + OFF_LAST;
  const float* WT_qy  = ws + OFF_QRY;

  // odd strides (129 / 65) so cross-row strided reads spread across LDS banks
  __shared__ float hist[SS][129];      // phase0: E rows; loop: state history
  __shared__ float G[52][65];          // Gram rows tq=12..63 (row = tq-12)
  __shared__ int   idxk[SS][RK];
  __shared__ float kwh[SS];            // cached w_k . tanh(Wq . state + bq)
  __shared__ float m_[5][D];
  __shared__ float a_[5][D];
  __shared__ float xv[2*D];
  __shared__ float gi[3*D];
  __shared__ float gh[3*D];
  __shared__ float h1[D], h2[D], g2[D], e0[D], qcs[D];
  __shared__ int   sq[SS], scc[SS], smk[SS];
  __shared__ int   n1[QN], n2[QN*CN], c2[MAXC];
  __shared__ float red[8];
  __shared__ float ogv[16], kwv[16];

  // ---- phase 0: preload sequences ----
  for (int i = tid; i < SS; i += T) { sq[i]=qseq[b*SS+i]; scc[i]=cseq[b*SS+i]; smk[i]=mseq[b*SS+i]; }
  __syncthreads();

  // gather E rows (embed_question of this row's sequence) into hist[]
  for (int i = tid; i < SS*D; i += T) { int s = i >> 7, d = i & 127; hist[s][d] = embQ[sq[s]*D + d]; }
  __syncthreads();

  // Gram scores: G[tq-12][s] = E[tq].E[s]  (needed for step t=tq-1, s<t)
  for (int p = tid; p < SS*SS; p += T) {
    int tq = p >> 6, s = p & 63;
    if (tq >= RK+2 && s < tq-1) {
      float acc = 0.f;
      #pragma unroll 8
      for (int d = 0; d < D; ++d) acc += hist[tq][d]*hist[s][d];
      G[tq-(RK+2)][s] = acc;
    }
  }
  __syncthreads();

  // stable top-k (ties -> lowest index, matching jax.lax.top_k)
  if (tid < 52) {
    int t = RK + 1 + tid;          // 11..62
    for (int k = 0; k < RK; ++k) {
      float best = -INFINITY; int bi = 0;
      for (int s = 0; s < t; ++s) { float v = G[tid][s]; if (v > best) { best = v; bi = s; } }
      idxk[t][k] = bi;
      G[tid][bi] = -INFINITY;
    }
  }
  __syncthreads();

  // init state
  if (tid < D) { hist[0][tid] = 0.f; h1[tid] = h1i[b*D+tid]; h2[tid] = h2i[b*D+tid]; }
  if (tid == 0) y[b*SS + 1] = 0.f;   // never written by reference
  {
    float p0 = (tid < D) ? w_k[tid]*tanhf(b_query[tid]) : 0.f;   // kw of zero-state row
    #pragma unroll
    for (int off = 32; off; off >>= 1) p0 += __shfl_down(p0, off);
    if ((tid & 63) == 0) red[tid >> 6] = p0;
  }
  __syncthreads();
  if (tid == 0) kwh[0] = red[0]+red[1]+red[2]+red[3]+red[4]+red[5];
  __syncthreads();

  // ---- sequential time loop ----
  for (int t = 0; t < SS-1; ++t) {
    const int qt  = sq[t];
    const int qnx = sq[t+1];

    if (tid < QN) n1[tid] = qnbr[qt*QN + tid];
    else if (tid >= 8 && tid < 8+MAXC) c2[tid-8] = q2c[qnx*MAXC + (tid-8)];
    __syncthreads();
    if (tid < QN*CN) n2[tid] = cnbr[n1[tid>>2]*CN + (tid&3)];
    __syncthreads();

    // gathers + neighbor means
    {
      const int d   = tid & 127;
      const int grp = tid >> 7;
      if (grp == 0) {
        float ev = embQ[qt*D + d];
        e0[d] = ev;
        float s1 = embC[n1[0]*D+d]+embC[n1[1]*D+d]+embC[n1[2]*D+d]+embC[n1[3]*D+d];
        m_[0][d] = ev + 0.25f*s1;
        xv[D + d] = embR[scc[t]*D + d];          // emb_r -> second half of GRU1 input
      } else {
        const int j0 = (grp-1)*2;
        #pragma unroll
        for (int jj = 0; jj < 2; ++jj) {
          int j = j0 + jj;
          float e1v = embC[n1[j]*D + d];
          float s2  = embQ[n2[j*CN+0]*D+d]+embQ[n2[j*CN+1]*D+d]
                     +embQ[n2[j*CN+2]*D+d]+embQ[n2[j*CN+3]*D+d];
          m_[1+j][d] = e1v + 0.25f*s2;
        }
      }
    }
    __syncthreads();

    // agg stage 1: a0 = tanh(W0 m0 + b0); a1[j] = tanh(W1 m1[j] + b1)
    {
      const int r   = tid & 127;
      const int grp = tid >> 7;
      if (grp == 0) {
        float acc = b_agg[r];
        #pragma unroll 8
        for (int e = 0; e < D; ++e) acc += WT_a0[e*D + r]*m_[0][e];
        a_[0][r] = tanhf(acc);
      } else {
        const int j0 = (grp-1)*2;
        float acc0 = b_agg[D + r], acc1 = acc0;
        #pragma unroll 8
        for (int e = 0; e < D; ++e) { float w = WT_a1[e*D + r]; acc0 += w*m_[1+j0][e]; acc1 += w*m_[2+j0][e]; }
        a_[1+j0][r] = tanhf(acc0);
        a_[2+j0][r] = tanhf(acc1);
      }
    }
    __syncthreads();

    // agg stage 2 mean; idle threads build qc-sum for predict (independent work)
    if (tid < D) m_[0][tid] = a_[0][tid] + 0.25f*(a_[1][tid]+a_[2][tid]+a_[3][tid]+a_[4][tid]);
    else if (tid < 2*D) {
      const int d = tid - D;
      float acc = embQ[qnx*D + d];
      #pragma unroll
      for (int mm = 0; mm < MAXC; ++mm) acc += embC[c2[mm]*D + d];
      qcs[d] = acc;
    }
    __syncthreads();

    if (tid < D) {
      float acc = b_agg[tid];
      #pragma unroll 8
      for (int e = 0; e < D; ++e) acc += WT_a0[e*D + tid]*m_[0][e];
      a_[0][tid] = tanhf(acc);
    }
    __syncthreads();

    // agg last + mask select -> GRU1 input first half
    if (tid < D) {
      float acc = b_last[tid];
      #pragma unroll 8
      for (int e = 0; e < D; ++e) acc += WT_ls[e*D + tid]*a_[0][e];
      float aggv = tanhf(acc);
      xv[tid] = smk[t] ? aggv : e0[tid];
    }
    __syncthreads();

    // GRU1: one output row per thread (r = tid, 384 rows)
    {
      const int r = tid;
      float acc = b_ih1[r];
      #pragma unroll 8
      for (int e = 0; e < 2*D; ++e) acc += WT_ih1[e*384 + r]*xv[e];
      gi[r] = acc;
      float acc2 = b_hh1[r];
      #pragma unroll 8
      for (int e = 0; e < D; ++e) acc2 += WT_hh1[e*384 + r]*h1[e];
      gh[r] = acc2;
    }
    __syncthreads();
    if (tid < D) {
      float rg = 1.f/(1.f + expf(-(gi[tid]+gh[tid])));
      float zg = 1.f/(1.f + expf(-(gi[D+tid]+gh[D+tid])));
      float ng = tanhf(gi[2*D+tid] + rg*gh[2*D+tid]);
      h1[tid] = (1.f-zg)*ng + zg*h1[tid];
    }
    __syncthreads();

    // GRU2
    {
      const int r = tid;
      float acc = b_ih2[r];
      #pragma unroll 8
      for (int e = 0; e < D; ++e) acc += WT_ih2[e*384 + r]*h1[e];
      gi[r] = acc;
      float acc2 = b_hh2[r];
      #pragma unroll 8
      for (int e = 0; e < D; ++e) acc2 += WT_hh2[e*384 + r]*h2[e];
      gh[r] = acc2;
    }
    __syncthreads();
    if (tid < D) {
      float rg = 1.f/(1.f + expf(-(gi[tid]+gh[tid])));
      float zg = 1.f/(1.f + expf(-(gi[D+tid]+gh[D+tid])));
      float ng = tanhf(gi[2*D+tid] + rg*gh[2*D+tid]);
      g2[tid] = (1.f-zg)*ng + zg*h2[tid];
    }
    __syncthreads();

    // kw_cur = w_k . tanh(W_query g2 + b_query)   (softmax logits; query side cancels)
    float kep = 0.f;
    if (tid < D) {
      float acc = b_query[tid];
      #pragma unroll 8
      for (int e = 0; e < D; ++e) acc += WT_qy[e*D + tid]*g2[e];
      kep = tanhf(acc) * w_k[tid];
    }
    #pragma unroll
    for (int off = 32; off; off >>= 1) kep += __shfl_down(kep, off);
    if ((tid & 63) == 0) red[tid >> 6] = kep;
    __syncthreads();

    const int ne = (t < RK ? t : RK) + 1;   // #attention entries = 1 (cur) + L
    if (tid == 0) {
      float v = red[0]+red[1]+red[2]+red[3]+red[4]+red[5];
      kwv[0] = v;
      if (t >= 1) kwh[t] = v;
    }
    // og dots: one 16-lane group per attention entry
    {
      const int g = tid >> 4, lane = tid & 15;
      if (g < ne) {
        const float* row;
        if (g == 0) row = g2;
        else {
          int s = (t <= RK) ? (g-1) : idxk[t][g-1];
          row = hist[s];
          if (lane == 0) kwv[g] = kwh[s];
        }
        float part = 0.f;
        #pragma unroll
        for (int k = 0; k < 8; ++k) { int d = lane + (k<<4); part += qcs[d]*row[d]; }
        part += __shfl_xor(part, 8, 16);
        part += __shfl_xor(part, 4, 16);
        part += __shfl_xor(part, 2, 16);
        part += __shfl_xor(part, 1, 16);
        if (lane == 0) ogv[g] = part;
      }
    }
    __syncthreads();

    if (tid == 0) {
      float mx = kwv[0];
      for (int i2 = 1; i2 < ne; ++i2) mx = fmaxf(mx, kwv[i2]);
      float den = 0.f, num = 0.f;
      for (int i2 = 0; i2 < ne; ++i2) { float e_ = expf(kwv[i2]-mx); den += e_; num += e_*ogv[i2]; }
      float val = num/den;
      y[b*SS + ((t==0) ? 0 : (t+1))] = 1.f/(1.f + expf(-val));
    }
    // state updates (skipped at t==0, matching the reference's `continue`)
    if (t >= 1 && tid < D) { hist[t][tid] = g2[tid]; h2[tid] = g2[tid]; }
    __syncthreads();
  }
}

extern "C" void kernel_launch(void* const* d_in, const int* in_sizes, int n_in,
                              void* d_out, int out_size, void* d_ws, size_t ws_size,
                              hipStream_t stream)
{
  (void)in_sizes; (void)n_in; (void)out_size; (void)ws_size;

  const float* embQ  = (const float*)d_in[0];
  const float* embC  = (const float*)d_in[1];
  const float* embR  = (const float*)d_in[2];
  const float* Wih1  = (const float*)d_in[3];
  const float* Whh1  = (const float*)d_in[4];
  const float* bih1  = (const float*)d_in[5];
  const float* bhh1  = (const float*)d_in[6];
  const float* Wih2  = (const float*)d_in[7];
  const float* Whh2  = (const float*)d_in[8];
  const float* bih2  = (const float*)d_in[9];
  const float* bhh2  = (const float*)d_in[10];
  const float* Wagg  = (const float*)d_in[11];
  const float* bagg  = (const float*)d_in[12];
  const float* Wlast = (const float*)d_in[13];
  const float* blast = (const float*)d_in[14];
  const float* Wqry  = (const float*)d_in[15];
  const float* bqry  = (const float*)d_in[16];
  // d_in[17] W_key, d_in[18] b_key, d_in[19] w_q, d_in[21] b_w: cancel in softmax -> unused
  const float* wk    = (const float*)d_in[20];
  const float* h1i   = (const float*)d_in[22];
  const float* h2i   = (const float*)d_in[23];
  const int* qnbr    = (const int*)d_in[24];
  const int* cnbr    = (const int*)d_in[25];
  const int* q2c     = (const int*)d_in[26];
  const int* qseq    = (const int*)d_in[27];
  const int* cseq    = (const int*)d_in[28];
  const int* mseq    = (const int*)d_in[29];

  float* ws = (float*)d_ws;
  float* y  = (float*)d_out;

  gikt_transpose<<<(WS_FLOATS+511)/512, 512, 0, stream>>>(Wih1, Whh1, Wih2, Whh2, Wagg, Wlast, Wqry, ws);
  gikt_main<<<BB, T, 0, stream>>>(embQ, embC, embR, bih1, bhh1, bih2, bhh2, bagg, blast, bqry,
                                  wk, h1i, h2i, qnbr, cnbr, q2c, qseq, cseq, mseq, ws, y);
}

// Round 2
// 1748.559 us; speedup vs baseline: 1.0109x; 1.0109x over previous
//
#include <hip/hip_runtime.h>
#include <math.h>

#define D    128
#define QN   4
#define CN   4
#define MAXC 4
#define BB   128
#define SS   64
#define RK   10
#define T    768   // 12 waves

// transposed-weight workspace layout (floats); each matrix stored as
// float4 tiles [E/4][R]: flat float index (e4*R + r)*4 + c = W[r][4*e4+c]
#define SZ_IH1  (256*384)
#define SZ_HH1  (128*384)
#define SZ_SQ   (128*128)
#define OFF_IH1  0
#define OFF_HH1  (OFF_IH1 + SZ_IH1)
#define OFF_IH2  (OFF_HH1 + SZ_HH1)
#define OFF_HH2  (OFF_IH2 + SZ_HH1)
#define OFF_AGG0 (OFF_HH2 + SZ_HH1)
#define OFF_AGG1 (OFF_AGG0 + SZ_SQ)
#define OFF_LAST (OFF_AGG1 + SZ_SQ)
#define OFF_QRY  (OFF_LAST + SZ_SQ)
#define WS_FLOATS (OFF_QRY + SZ_SQ)

__global__ void gikt_transpose(const float* __restrict__ Wih1,
                               const float* __restrict__ Whh1,
                               const float* __restrict__ Wih2,
                               const float* __restrict__ Whh2,
                               const float* __restrict__ Wagg,
                               const float* __restrict__ Wlast,
                               const float* __restrict__ Wqry,
                               float* __restrict__ ws)
{
  int i = blockIdx.x * blockDim.x + threadIdx.x;
  if (i >= WS_FLOATS) return;
  int j = i;
  if (j < SZ_IH1) { int c=j&3, f4=j>>2, e4=f4/384, r=f4-e4*384; ws[i] = Wih1[r*256 + e4*4 + c]; return; }
  j -= SZ_IH1;
  if (j < SZ_HH1) { int c=j&3, f4=j>>2, e4=f4/384, r=f4-e4*384; ws[i] = Whh1[r*128 + e4*4 + c]; return; }
  j -= SZ_HH1;
  if (j < SZ_HH1) { int c=j&3, f4=j>>2, e4=f4/384, r=f4-e4*384; ws[i] = Wih2[r*128 + e4*4 + c]; return; }
  j -= SZ_HH1;
  if (j < SZ_HH1) { int c=j&3, f4=j>>2, e4=f4/384, r=f4-e4*384; ws[i] = Whh2[r*128 + e4*4 + c]; return; }
  j -= SZ_HH1;
  if (j < SZ_SQ)  { int c=j&3, f4=j>>2, e4=f4>>7, r=f4&127; ws[i] = Wagg[r*128 + e4*4 + c]; return; }
  j -= SZ_SQ;
  if (j < SZ_SQ)  { int c=j&3, f4=j>>2, e4=f4>>7, r=f4&127; ws[i] = Wagg[128*128 + r*128 + e4*4 + c]; return; }
  j -= SZ_SQ;
  if (j < SZ_SQ)  { int c=j&3, f4=j>>2, e4=f4>>7, r=f4&127; ws[i] = Wlast[r*128 + e4*4 + c]; return; }
  j -= SZ_SQ;
  { int c=j&3, f4=j>>2, e4=f4>>7, r=f4&127; ws[i] = Wqry[r*128 + e4*4 + c]; }
}

__launch_bounds__(T, 1)
__global__ void gikt_main(
    const float* __restrict__ embQ,
    const float* __restrict__ embC,
    const float* __restrict__ embR,
    const float* __restrict__ b_ih1,
    const float* __restrict__ b_hh1,
    const float* __restrict__ b_ih2,
    const float* __restrict__ b_hh2,
    const float* __restrict__ b_agg,
    const float* __restrict__ b_last,
    const float* __restrict__ b_query,
    const float* __restrict__ w_k,
    const float* __restrict__ h1i,
    const float* __restrict__ h2i,
    const int* __restrict__ qnbr,
    const int* __restrict__ cnbr,
    const int* __restrict__ q2c,
    const int* __restrict__ qseq,
    const int* __restrict__ cseq,
    const int* __restrict__ mseq,
    const float* __restrict__ ws,
    float* __restrict__ y)
{
  const int b   = blockIdx.x;
  const int tid = threadIdx.x;

  const float* WT_ih1 = ws + OFF_IH1;  // f4 tiles [64][384]
  const float* WT_hh1 = ws + OFF_HH1;  // [32][384]
  const float* WT_ih2 = ws + OFF_IH2;
  const float* WT_hh2 = ws + OFF_HH2;
  const float* WT_a0  = ws + OFF_AGG0; // [32][128]
  const float* WT_a1  = ws + OFF_AGG1;
  const float* WT_ls  = ws + OFF_LAST;
  const float* WT_qy  = ws + OFF_QRY;

  __shared__ float hist[SS][129];      // phase0: E rows; loop: state history
  __shared__ float G[52][65];          // Gram rows tq=12..63 (row = tq-12)
  __shared__ int   idxk[SS][RK];
  __shared__ float kwh[SS];
  __shared__ __align__(16) float m_[5][D];
  __shared__ __align__(16) float a_[5][D];
  __shared__ __align__(16) float xv[2*D];
  __shared__ float gi[3*D];
  __shared__ float gh[3*D];
  __shared__ __align__(16) float h1[D];
  __shared__ __align__(16) float h2[D];
  __shared__ __align__(16) float g2[D];
  __shared__ float e0[D], qcs[D];
  __shared__ int   sq[SS], scc[SS], smk[SS];
  __shared__ int   n1[QN], n2[QN*CN], c2[MAXC];
  __shared__ float red[12];
  __shared__ float ogv[16], kwv[16];

  // ---- phase 0: preload sequences ----
  for (int i = tid; i < SS; i += T) { sq[i]=qseq[b*SS+i]; scc[i]=cseq[b*SS+i]; smk[i]=mseq[b*SS+i]; }
  __syncthreads();

  // gather E rows (embed_question of this row's sequence) into hist[]
  for (int i = tid; i < SS*32; i += T) {
    int s = i >> 5, e4 = i & 31;
    float4 v = ((const float4*)(embQ + sq[s]*D))[e4];
    hist[s][e4*4+0] = v.x; hist[s][e4*4+1] = v.y; hist[s][e4*4+2] = v.z; hist[s][e4*4+3] = v.w;
  }
  __syncthreads();

  // Gram scores: G[tq-12][s] = E[tq].E[s]
  for (int p = tid; p < SS*SS; p += T) {
    int tq = p >> 6, s = p & 63;
    if (tq >= RK+2 && s < tq-1) {
      float acc = 0.f;
      #pragma unroll 8
      for (int d = 0; d < D; ++d) acc += hist[tq][d]*hist[s][d];
      G[tq-(RK+2)][s] = acc;
    }
  }
  __syncthreads();

  // stable top-k (ties -> lowest index, matching jax.lax.top_k)
  if (tid < 52) {
    int t = RK + 1 + tid;          // 11..62
    for (int k = 0; k < RK; ++k) {
      float best = -INFINITY; int bi = 0;
      for (int s = 0; s < t; ++s) { float v = G[tid][s]; if (v > best) { best = v; bi = s; } }
      idxk[t][k] = bi;
      G[tid][bi] = -INFINITY;
    }
  }
  __syncthreads();

  // init state
  if (tid < D) { hist[0][tid] = 0.f; h1[tid] = h1i[b*D+tid]; h2[tid] = h2i[b*D+tid]; }
  if (tid == 0) y[b*SS + 1] = 0.f;   // never written by reference
  {
    float p0 = (tid < D) ? w_k[tid]*tanhf(b_query[tid]) : 0.f;   // kw of zero-state row
    #pragma unroll
    for (int off = 32; off; off >>= 1) p0 += __shfl_down(p0, off);
    if ((tid & 63) == 0) red[tid >> 6] = p0;
  }
  __syncthreads();
  if (tid == 0) kwh[0] = red[0]+red[1];
  __syncthreads();

  // ---- sequential time loop ----
  for (int t = 0; t < SS-1; ++t) {
    const int qt  = sq[t];
    const int qnx = sq[t+1];

    if (tid < QN) n1[tid] = qnbr[qt*QN + tid];
    else if (tid >= 64 && tid < 64+MAXC) c2[tid-64] = q2c[qnx*MAXC + (tid-64)];
    __syncthreads();
    if (tid < QN*CN) n2[tid] = cnbr[n1[tid>>2]*CN + (tid&3)];
    __syncthreads();

    // gathers + neighbor means + qc-sum (6 groups of 128)
    {
      const int d   = tid & 127;
      const int grp = tid >> 7;
      if (grp == 0) {
        float ev = embQ[qt*D + d];
        e0[d] = ev;
        float s1 = embC[n1[0]*D+d]+embC[n1[1]*D+d]+embC[n1[2]*D+d]+embC[n1[3]*D+d];
        m_[0][d] = ev + 0.25f*s1;
      } else if (grp <= 4) {
        const int j = grp - 1;
        float e1v = embC[n1[j]*D + d];
        float s2  = embQ[n2[j*CN+0]*D+d]+embQ[n2[j*CN+1]*D+d]
                   +embQ[n2[j*CN+2]*D+d]+embQ[n2[j*CN+3]*D+d];
        m_[grp][d] = e1v + 0.25f*s2;
      } else {
        xv[D + d] = embR[scc[t]*D + d];          // emb_r -> GRU1 input second half
        float acc = embQ[qnx*D + d];
        #pragma unroll
        for (int mm = 0; mm < MAXC; ++mm) acc += embC[c2[mm]*D + d];
        qcs[d] = acc;
      }
    }
    __syncthreads();

    // agg stage 1: 640 rows (a0: W0 m0; a1..a4: W1 m1..m4), 1 thread/row
    if (tid < 640) {
      const int which = tid >> 7, r = tid & 127;
      const float4* W4 = (const float4*)(which == 0 ? WT_a0 : WT_a1);
      const float4* x4 = (const float4*)m_[which];
      float accb = (which == 0) ? b_agg[r] : b_agg[D + r];
      float4 a4 = {0.f,0.f,0.f,0.f};
      #pragma unroll 16
      for (int e4 = 0; e4 < 32; ++e4) {
        float4 w = W4[e4*128 + r]; float4 x = x4[e4];
        a4.x += w.x*x.x; a4.y += w.y*x.y; a4.z += w.z*x.z; a4.w += w.w*x.w;
      }
      a_[which][r] = tanhf(accb + (a4.x+a4.y) + (a4.z+a4.w));
    }
    __syncthreads();

    // agg stage 2 mean
    if (tid < D) m_[0][tid] = a_[0][tid] + 0.25f*(a_[1][tid]+a_[2][tid]+a_[3][tid]+a_[4][tid]);
    __syncthreads();

    // agg stage 2 matvec (2 threads/row)
    if (tid < 256) {
      const int r = tid >> 1, hf = tid & 1;
      const float4* W4 = (const float4*)WT_a0;
      const float4* x4 = (const float4*)m_[0];
      float acc = hf ? 0.f : b_agg[r];
      float4 a4 = {0.f,0.f,0.f,0.f};
      #pragma unroll
      for (int e4 = hf*16; e4 < hf*16+16; ++e4) {
        float4 w = W4[e4*128 + r]; float4 x = x4[e4];
        a4.x += w.x*x.x; a4.y += w.y*x.y; a4.z += w.z*x.z; a4.w += w.w*x.w;
      }
      acc += (a4.x+a4.y) + (a4.z+a4.w);
      acc += __shfl_xor(acc, 1);
      if (!hf) a_[0][r] = tanhf(acc);
    }
    __syncthreads();

    // agg last + mask select -> GRU1 input first half
    if (tid < 256) {
      const int r = tid >> 1, hf = tid & 1;
      const float4* W4 = (const float4*)WT_ls;
      const float4* x4 = (const float4*)a_[0];
      float acc = hf ? 0.f : b_last[r];
      float4 a4 = {0.f,0.f,0.f,0.f};
      #pragma unroll
      for (int e4 = hf*16; e4 < hf*16+16; ++e4) {
        float4 w = W4[e4*128 + r]; float4 x = x4[e4];
        a4.x += w.x*x.x; a4.y += w.y*x.y; a4.z += w.z*x.z; a4.w += w.w*x.w;
      }
      acc += (a4.x+a4.y) + (a4.z+a4.w);
      acc += __shfl_xor(acc, 1);
      if (!hf) xv[r] = smk[t] ? tanhf(acc) : e0[r];
    }
    __syncthreads();

    // GRU1: gi rows on tids 0..383 (64 f4), gh rows on tids 384..767 (32 f4)
    if (tid < 384) {
      const int r = tid;
      const float4* W4 = (const float4*)WT_ih1;
      const float4* x4 = (const float4*)xv;
      float4 a4 = {0.f,0.f,0.f,0.f};
      #pragma unroll 16
      for (int e4 = 0; e4 < 64; ++e4) {
        float4 w = W4[e4*384 + r]; float4 x = x4[e4];
        a4.x += w.x*x.x; a4.y += w.y*x.y; a4.z += w.z*x.z; a4.w += w.w*x.w;
      }
      gi[r] = b_ih1[r] + (a4.x+a4.y) + (a4.z+a4.w);
    } else {
      const int r = tid - 384;
      const float4* W4 = (const float4*)WT_hh1;
      const float4* x4 = (const float4*)h1;
      float4 a4 = {0.f,0.f,0.f,0.f};
      #pragma unroll 16
      for (int e4 = 0; e4 < 32; ++e4) {
        float4 w = W4[e4*384 + r]; float4 x = x4[e4];
        a4.x += w.x*x.x; a4.y += w.y*x.y; a4.z += w.z*x.z; a4.w += w.w*x.w;
      }
      gh[r] = b_hh1[r] + (a4.x+a4.y) + (a4.z+a4.w);
    }
    __syncthreads();
    if (tid < D) {
      float rg = 1.f/(1.f + expf(-(gi[tid]+gh[tid])));
      float zg = 1.f/(1.f + expf(-(gi[D+tid]+gh[D+tid])));
      float ng = tanhf(gi[2*D+tid] + rg*gh[2*D+tid]);
      h1[tid] = (1.f-zg)*ng + zg*h1[tid];
    }
    __syncthreads();

    // GRU2
    if (tid < 384) {
      const int r = tid;
      const float4* W4 = (const float4*)WT_ih2;
      const float4* x4 = (const float4*)h1;
      float4 a4 = {0.f,0.f,0.f,0.f};
      #pragma unroll 16
      for (int e4 = 0; e4 < 32; ++e4) {
        float4 w = W4[e4*384 + r]; float4 x = x4[e4];
        a4.x += w.x*x.x; a4.y += w.y*x.y; a4.z += w.z*x.z; a4.w += w.w*x.w;
      }
      gi[r] = b_ih2[r] + (a4.x+a4.y) + (a4.z+a4.w);
    } else {
      const int r = tid - 384;
      const float4* W4 = (const float4*)WT_hh2;
      const float4* x4 = (const float4*)h2;
      float4 a4 = {0.f,0.f,0.f,0.f};
      #pragma unroll 16
      for (int e4 = 0; e4 < 32; ++e4) {
        float4 w = W4[e4*384 + r]; float4 x = x4[e4];
        a4.x += w.x*x.x; a4.y += w.y*x.y; a4.z += w.z*x.z; a4.w += w.w*x.w;
      }
      gh[r] = b_hh2[r] + (a4.x+a4.y) + (a4.z+a4.w);
    }
    __syncthreads();
    if (tid < D) {
      float rg = 1.f/(1.f + expf(-(gi[tid]+gh[tid])));
      float zg = 1.f/(1.f + expf(-(gi[D+tid]+gh[D+tid])));
      float ng = tanhf(gi[2*D+tid] + rg*gh[2*D+tid]);
      g2[tid] = (1.f-zg)*ng + zg*h2[tid];
    }
    __syncthreads();

    // kw_cur = w_k . tanh(W_query g2 + b_query)   (2 threads/row + block reduce)
    float kep = 0.f;
    if (tid < 256) {
      const int r = tid >> 1, hf = tid & 1;
      const float4* W4 = (const float4*)WT_qy;
      const float4* x4 = (const float4*)g2;
      float acc = hf ? 0.f : b_query[r];
      float4 a4 = {0.f,0.f,0.f,0.f};
      #pragma unroll
      for (int e4 = hf*16; e4 < hf*16+16; ++e4) {
        float4 w = W4[e4*128 + r]; float4 x = x4[e4];
        a4.x += w.x*x.x; a4.y += w.y*x.y; a4.z += w.z*x.z; a4.w += w.w*x.w;
      }
      acc += (a4.x+a4.y) + (a4.z+a4.w);
      acc += __shfl_xor(acc, 1);
      if (!hf) kep = tanhf(acc) * w_k[r];
    }
    #pragma unroll
    for (int off = 32; off; off >>= 1) kep += __shfl_down(kep, off);
    if ((tid & 63) == 0) red[tid >> 6] = kep;
    __syncthreads();

    const int ne = (t < RK ? t : RK) + 1;
    if (tid == 0) {
      float v = red[0]+red[1]+red[2]+red[3];
      kwv[0] = v;
      if (t >= 1) kwh[t] = v;
    }
    // og dots: one 16-lane group per attention entry
    {
      const int g = tid >> 4, lane = tid & 15;
      if (g < ne) {
        const float* row;
        if (g == 0) row = g2;
        else {
          int s = (t <= RK) ? (g-1) : idxk[t][g-1];
          row = hist[s];
          if (lane == 0) kwv[g] = kwh[s];
        }
        float part = 0.f;
        #pragma unroll
        for (int k = 0; k < 8; ++k) { int d = lane + (k<<4); part += qcs[d]*row[d]; }
        part += __shfl_xor(part, 8, 16);
        part += __shfl_xor(part, 4, 16);
        part += __shfl_xor(part, 2, 16);
        part += __shfl_xor(part, 1, 16);
        if (lane == 0) ogv[g] = part;
      }
    }
    __syncthreads();

    if (tid == 0) {
      float mx = kwv[0];
      for (int i2 = 1; i2 < ne; ++i2) mx = fmaxf(mx, kwv[i2]);
      float den = 0.f, num = 0.f;
      for (int i2 = 0; i2 < ne; ++i2) { float e_ = expf(kwv[i2]-mx); den += e_; num += e_*ogv[i2]; }
      float val = num/den;
      y[b*SS + ((t==0) ? 0 : (t+1))] = 1.f/(1.f + expf(-val));
    }
    // state updates (skipped at t==0, matching the reference's `continue`)
    if (t >= 1 && tid < D) { hist[t][tid] = g2[tid]; h2[tid] = g2[tid]; }
    __syncthreads();
  }
}

extern "C" void kernel_launch(void* const* d_in, const int* in_sizes, int n_in,
                              void* d_out, int out_size, void* d_ws, size_t ws_size,
                              hipStream_t stream)
{
  (void)in_sizes; (void)n_in; (void)out_size; (void)ws_size;

  const float* embQ  = (const float*)d_in[0];
  const float* embC  = (const float*)d_in[1];
  const float* embR  = (const float*)d_in[2];
  const float* Wih1  = (const float*)d_in[3];
  const float* Whh1  = (const float*)d_in[4];
  const float* bih1  = (const float*)d_in[5];
  const float* bhh1  = (const float*)d_in[6];
  const float* Wih2  = (const float*)d_in[7];
  const float* Whh2  = (const float*)d_in[8];
  const float* bih2  = (const float*)d_in[9];
  const float* bhh2  = (const float*)d_in[10];
  const float* Wagg  = (const float*)d_in[11];
  const float* bagg  = (const float*)d_in[12];
  const float* Wlast = (const float*)d_in[13];
  const float* blast = (const float*)d_in[14];
  const float* Wqry  = (const float*)d_in[15];
  const float* bqry  = (const float*)d_in[16];
  // d_in[17] W_key, d_in[18] b_key, d_in[19] w_q, d_in[21] b_w: cancel in softmax -> unused
  const float* wk    = (const float*)d_in[20];
  const float* h1i   = (const float*)d_in[22];
  const float* h2i   = (const float*)d_in[23];
  const int* qnbr    = (const int*)d_in[24];
  const int* cnbr    = (const int*)d_in[25];
  const int* q2c     = (const int*)d_in[26];
  const int* qseq    = (const int*)d_in[27];
  const int* cseq    = (const int*)d_in[28];
  const int* mseq    = (const int*)d_in[29];

  float* ws = (float*)d_ws;
  float* y  = (float*)d_out;

  gikt_transpose<<<(WS_FLOATS+511)/512, 512, 0, stream>>>(Wih1, Whh1, Wih2, Whh2, Wagg, Wlast, Wqry, ws);
  gikt_main<<<BB, T, 0, stream>>>(embQ, embC, embR, bih1, bhh1, bih2, bhh2, bagg, blast, bqry,
                                  wk, h1i, h2i, qnbr, cnbr, q2c, qseq, cseq, mseq, ws, y);
}

// Round 3
// 1129.711 us; speedup vs baseline: 1.5647x; 1.5478x over previous
//
#include <hip/hip_runtime.h>
#include <math.h>

#define D    128
#define QN   4
#define CN   4
#define MAXC 4
#define BB   128
#define SS   64
#define RK   10
#define T    768   // 12 waves

// ---- packed-bf16 weight workspace layout (uint32 units; each uint = 2 bf16) ----
// chunked matrices: flat uint4 index k*NT + tid, thread tid=(2r+hf), elem e2 = hf*EH + k*4 + j
#define UOFF_IH1A 0        // cols 0..127 of W_ih1: NT=768,K=8  -> 24576 uints
#define UOFF_IH1B 24576    // cols 128..255 of W_ih1: [e2l][384] -> 24576
#define UOFF_HH1  49152    // NT=768,K=8 -> 24576
#define UOFF_IH2  73728    // NT=768,K=8 (pinned in regs) -> 24576
#define UOFF_HH2  98304    // NT=768,K=8 (pinned) -> 24576
#define UOFF_QRY  122880   // NT=256,K=8 -> 8192
#define UOFF_A0   131072   // paired [e2g][128][2] -> 8192
#define UOFF_A1   139264   // -> 8192
#define UOFF_LS   147456   // -> 8192
#define TOTAL_U   155648

__device__ __forceinline__ unsigned bf1(float x){
  unsigned u = __float_as_uint(x);
  return (u + 0x7fffu + ((u >> 16) & 1u)) >> 16;   // RNE fp32->bf16
}
__device__ __forceinline__ float uflo(unsigned u){ return __uint_as_float(u << 16); }
__device__ __forceinline__ float ufhi(unsigned u){ return __uint_as_float(u & 0xffff0000u); }

__global__ void gikt_pack(const float* __restrict__ Wih1,
                          const float* __restrict__ Whh1,
                          const float* __restrict__ Wih2,
                          const float* __restrict__ Whh2,
                          const float* __restrict__ Wagg,
                          const float* __restrict__ Wlast,
                          const float* __restrict__ Wqry,
                          unsigned* __restrict__ wsU)
{
  int i = blockIdx.x * blockDim.x + threadIdx.x;
  if (i >= TOTAL_U) return;
  const float* src = nullptr; int row = 0, e2 = 0, stride = 0;
  int j = i;
  if (j < 24576) {               // ih1a: chunked NT=768 K=8, e2 in [0,64) (cols 0..127)
    int c = j & 3, i4 = j >> 2, k = i4 / 768, t = i4 - k * 768, r = t >> 1, hf = t & 1;
    e2 = hf * 32 + k * 4 + c; row = r; src = Wih1; stride = 256;
  } else if ((j -= 24576) < 24576) {   // ih1b: [e2l][384], cols 128..255
    e2 = 64 + (j / 384); row = j % 384; src = Wih1; stride = 256;
  } else if ((j -= 24576) < 24576) {   // hh1
    int c = j & 3, i4 = j >> 2, k = i4 / 768, t = i4 - k * 768, r = t >> 1, hf = t & 1;
    e2 = hf * 32 + k * 4 + c; row = r; src = Whh1; stride = 128;
  } else if ((j -= 24576) < 24576) {   // ih2
    int c = j & 3, i4 = j >> 2, k = i4 / 768, t = i4 - k * 768, r = t >> 1, hf = t & 1;
    e2 = hf * 32 + k * 4 + c; row = r; src = Wih2; stride = 128;
  } else if ((j -= 24576) < 24576) {   // hh2
    int c = j & 3, i4 = j >> 2, k = i4 / 768, t = i4 - k * 768, r = t >> 1, hf = t & 1;
    e2 = hf * 32 + k * 4 + c; row = r; src = Whh2; stride = 128;
  } else if ((j -= 24576) < 8192) {    // qry: chunked NT=256 K=8
    int c = j & 3, i4 = j >> 2, k = i4 >> 8, t = i4 & 255, r = t >> 1, hf = t & 1;
    e2 = hf * 32 + k * 4 + c; row = r; src = Wqry; stride = 128;
  } else if ((j -= 8192) < 8192) {     // a0 paired: j = e2g*256 + 2r + p
    int p = j & 1, r = (j >> 1) & 127, e2g = j >> 8;
    e2 = 2 * e2g + p; row = r; src = Wagg; stride = 128;
  } else if ((j -= 8192) < 8192) {     // a1
    int p = j & 1, r = (j >> 1) & 127, e2g = j >> 8;
    e2 = 2 * e2g + p; row = r; src = Wagg + 128 * 128; stride = 128;
  } else {                              // ls
    j -= 8192;
    int p = j & 1, r = (j >> 1) & 127, e2g = j >> 8;
    e2 = 2 * e2g + p; row = r; src = Wlast; stride = 128;
  }
  float lo = src[row * stride + 2 * e2];
  float hi = src[row * stride + 2 * e2 + 1];
  wsU[i] = bf1(lo) | (bf1(hi) << 16);
}

#define DOT8(u4, xp, e2b, acc) {                                   \
  float2 x0=(xp)[(e2b)], x1=(xp)[(e2b)+1], x2=(xp)[(e2b)+2], x3=(xp)[(e2b)+3]; \
  acc += uflo(u4.x)*x0.x + ufhi(u4.x)*x0.y;                        \
  acc += uflo(u4.y)*x1.x + ufhi(u4.y)*x1.y;                        \
  acc += uflo(u4.z)*x2.x + ufhi(u4.z)*x2.y;                        \
  acc += uflo(u4.w)*x3.x + ufhi(u4.w)*x3.y; }

__launch_bounds__(T, 1)
__global__ void gikt_main(
    const float* __restrict__ embQ,
    const float* __restrict__ embC,
    const float* __restrict__ embR,
    const float* __restrict__ b_ih1,
    const float* __restrict__ b_hh1,
    const float* __restrict__ b_ih2,
    const float* __restrict__ b_hh2,
    const float* __restrict__ b_agg,
    const float* __restrict__ b_last,
    const float* __restrict__ b_query,
    const float* __restrict__ w_k,
    const float* __restrict__ h1i,
    const float* __restrict__ h2i,
    const int* __restrict__ qnbr,
    const int* __restrict__ cnbr,
    const int* __restrict__ q2c,
    const int* __restrict__ qseq,
    const int* __restrict__ cseq,
    const int* __restrict__ mseq,
    const unsigned* __restrict__ wsU,
    float* __restrict__ y)
{
  const int b   = blockIdx.x;
  const int tid = threadIdx.x;
  const int r2  = tid >> 1, hf = tid & 1;   // 2-threads-per-row mapping

  __shared__ unsigned aggL[3 * 8192];       // a0|a1|ls paired [e2g][128][2]; phase0: aliased as Gram G
  __shared__ float hist[SS][129];           // phase0: E rows; loop: state history (row 0 = zero state)
  __shared__ float gicorr[2][384];          // W_ih1[:,128:256] @ embR[c]
  __shared__ int   idxk[SS][RK];
  __shared__ float kwh[SS];
  __shared__ __align__(16) float m_[5][D];
  __shared__ __align__(16) float a_[5][D];
  __shared__ __align__(16) float xv[D];
  __shared__ float gi[3*D];
  __shared__ float gh[3*D];
  __shared__ __align__(16) float h1[D];
  __shared__ __align__(16) float h2[D];
  __shared__ __align__(16) float g2[D];
  __shared__ float e0[D], qcs[D];
  __shared__ int   sq[SS], scc[SS], smk[SS];
  __shared__ int   nn1[SS][QN], nn2[SS][QN*CN], cc2[SS][MAXC];
  __shared__ float red[12];
  __shared__ float ogv[16], kwv[16];

  float (*G)[65] = (float(*)[65])aggL;      // 52*65*4 = 13.5KB <= 96KB

  // ---- pinned GRU2 weights: 16 uint4 = 64 VGPRs/thread ----
  uint4 pwi[8], pwh[8];
  {
    const uint4* Pi = (const uint4*)(wsU + UOFF_IH2);
    const uint4* Ph = (const uint4*)(wsU + UOFF_HH2);
    #pragma unroll
    for (int k = 0; k < 8; ++k) { pwi[k] = Pi[k*768 + tid]; pwh[k] = Ph[k*768 + tid]; }
  }

  // ---- phase 0a: sequences ----
  for (int i = tid; i < SS; i += T) { sq[i]=qseq[b*SS+i]; scc[i]=cseq[b*SS+i]; smk[i]=mseq[b*SS+i]; }
  __syncthreads();

  // ---- phase 0b: E rows into hist; 1-hop indices ----
  for (int i = tid; i < SS*32; i += T) {
    int s = i >> 5, e4 = i & 31;
    float4 v = ((const float4*)(embQ + sq[s]*D))[e4];
    hist[s][e4*4+0] = v.x; hist[s][e4*4+1] = v.y; hist[s][e4*4+2] = v.z; hist[s][e4*4+3] = v.w;
  }
  for (int i = tid; i < (SS-1)*QN; i += T)   { int t = i>>2, j = i&3; nn1[t][j] = qnbr[sq[t]*QN + j]; }
  for (int i = tid; i < (SS-1)*MAXC; i += T) { int t = i>>2, j = i&3; cc2[t][j] = q2c[sq[t+1]*MAXC + j]; }
  __syncthreads();

  // ---- phase 0c: Gram (fp32, exact), 2-hop indices, gicorr precompute ----
  for (int p = tid; p < SS*SS; p += T) {
    int tq = p >> 6, s = p & 63;
    if (tq >= RK+2 && s < tq-1) {
      float acc = 0.f;
      #pragma unroll 8
      for (int d = 0; d < D; ++d) acc += hist[tq][d]*hist[s][d];
      G[tq-(RK+2)][s] = acc;
    }
  }
  for (int i = tid; i < (SS-1)*QN*CN; i += T) {
    int t = i>>4, j = (i>>2)&3, l = i&3;
    nn2[t][j*CN+l] = cnbr[nn1[t][j]*CN + l];
  }
  {
    // gicorr[c][r] = sum_e W_ih1[r][128+e] * embR[c][e]
    const int c = (tid >= 384) ? 1 : 0, r = tid - (c ? 384 : 0);
    const float2* er2 = (const float2*)(embR + c*D);
    float acc = 0.f;
    #pragma unroll 4
    for (int e2l = 0; e2l < 64; ++e2l) {
      unsigned u = wsU[UOFF_IH1B + e2l*384 + r];
      float2 x = er2[e2l];
      acc += uflo(u)*x.x + ufhi(u)*x.y;
    }
    gicorr[c][r] = acc;
  }
  __syncthreads();

  // ---- phase 0d: stable top-k (ties -> lowest index, = jax.lax.top_k) ----
  if (tid < 52) {
    int t = RK + 1 + tid;          // 11..62
    for (int k = 0; k < RK; ++k) {
      float best = -INFINITY; int bi = 0;
      for (int s = 0; s < t; ++s) { float v = G[tid][s]; if (v > best) { best = v; bi = s; } }
      idxk[t][k] = bi;
      G[tid][bi] = -INFINITY;
    }
  }
  __syncthreads();

  // ---- phase 0e: agg weights into LDS (overwrites G); state init; kw(zero-state) ----
  for (int i = tid; i < 3*8192; i += T) aggL[i] = wsU[UOFF_A0 + i];
  if (tid < D) { hist[0][tid] = 0.f; h1[tid] = h1i[b*D+tid]; h2[tid] = h2i[b*D+tid]; }
  if (tid == 0) y[b*SS + 1] = 0.f;   // never written by reference
  {
    float p0 = (tid < D) ? w_k[tid]*tanhf(b_query[tid]) : 0.f;
    #pragma unroll
    for (int off = 32; off; off >>= 1) p0 += __shfl_down(p0, off);
    if ((tid & 63) == 0) red[tid >> 6] = p0;
  }
  __syncthreads();

  const uint4* Wi1 = (const uint4*)(wsU + UOFF_IH1A);
  const uint4* Wh1 = (const uint4*)(wsU + UOFF_HH1);
  const uint4* Wq  = (const uint4*)(wsU + UOFF_QRY);
  const float2* h12 = (const float2*)h1;
  const float2* h22 = (const float2*)h2;
  const float2* xv2 = (const float2*)xv;
  const float2* g22 = (const float2*)g2;

  // ---- sequential time loop ----
  for (int t = 0; t < SS-1; ++t) {
    // finalize previous step's output (tid0 only; inputs all barrier-protected)
    if (tid == 0) {
      if (t == 0) {
        kwh[0] = red[0] + red[1];   // kw of zero state
      } else {
        const int tp = t - 1;
        const int ne = (tp < RK ? tp : RK) + 1;
        float cur = red[0]+red[1]+red[2]+red[3];
        kwv[0] = cur;
        if (tp >= 1) kwh[tp] = cur;
        float mx = kwv[0];
        for (int i2 = 1; i2 < ne; ++i2) mx = fmaxf(mx, kwv[i2]);
        float den = 0.f, num = 0.f;
        for (int i2 = 0; i2 < ne; ++i2) { float e_ = expf(kwv[i2]-mx); den += e_; num += e_*ogv[i2]; }
        float val = num/den;
        y[b*SS + ((tp==0) ? 0 : (tp+1))] = 1.f/(1.f + expf(-val));
      }
    }

    // ---- gather phase: 6 groups of 128 ----
    {
      const int d   = tid & 127;
      const int grp = tid >> 7;
      if (grp == 0) {
        float ev = embQ[sq[t]*D + d];
        e0[d] = ev;
        float s1 = embC[nn1[t][0]*D+d]+embC[nn1[t][1]*D+d]+embC[nn1[t][2]*D+d]+embC[nn1[t][3]*D+d];
        m_[0][d] = ev + 0.25f*s1;
      } else if (grp <= 4) {
        const int j = grp - 1;
        float e1v = embC[nn1[t][j]*D + d];
        float s2  = embQ[nn2[t][j*CN+0]*D+d]+embQ[nn2[t][j*CN+1]*D+d]
                   +embQ[nn2[t][j*CN+2]*D+d]+embQ[nn2[t][j*CN+3]*D+d];
        m_[grp][d] = e1v + 0.25f*s2;
      } else {
        float acc = embQ[sq[t+1]*D + d];
        #pragma unroll
        for (int mm = 0; mm < MAXC; ++mm) acc += embC[cc2[t][mm]*D + d];
        qcs[d] = acc;
      }
    }
    __syncthreads();

    // ---- agg stage 1 (LDS weights): 640 threads, 1/row ----
    if (tid < 640) {
      const int which = tid >> 7, r = tid & 127;
      const unsigned* A = aggL + (which == 0 ? 0 : 8192);
      const float4* x4p = (const float4*)m_[which];
      float acc = (which == 0) ? b_agg[r] : b_agg[D + r];
      #pragma unroll 8
      for (int e2g = 0; e2g < 32; ++e2g) {
        uint2 u = *(const uint2*)(A + e2g*256 + r*2);
        float4 x = x4p[e2g];
        acc += uflo(u.x)*x.x + ufhi(u.x)*x.y + uflo(u.y)*x.z + ufhi(u.y)*x.w;
      }
      a_[which][r] = tanhf(acc);
    }
    __syncthreads();

    // ---- agg stage 2 (mean folded in): 256 threads, 2/row -> m_[1] ----
    if (tid < 256) {
      const int r = tid >> 1, h = tid & 1;
      float acc = h ? 0.f : b_agg[r];
      #pragma unroll 4
      for (int e2g = h*16; e2g < h*16+16; ++e2g) {
        float4 a0v = ((const float4*)a_[0])[e2g];
        float4 a1v = ((const float4*)a_[1])[e2g];
        float4 a2v = ((const float4*)a_[2])[e2g];
        float4 a3v = ((const float4*)a_[3])[e2g];
        float4 a4v = ((const float4*)a_[4])[e2g];
        float4 x; x.x = a0v.x + 0.25f*(a1v.x+a2v.x+a3v.x+a4v.x);
                  x.y = a0v.y + 0.25f*(a1v.y+a2v.y+a3v.y+a4v.y);
                  x.z = a0v.z + 0.25f*(a1v.z+a2v.z+a3v.z+a4v.z);
                  x.w = a0v.w + 0.25f*(a1v.w+a2v.w+a3v.w+a4v.w);
        uint2 u = *(const uint2*)(aggL + e2g*256 + r*2);
        acc += uflo(u.x)*x.x + ufhi(u.x)*x.y + uflo(u.y)*x.z + ufhi(u.y)*x.w;
      }
      acc += __shfl_xor(acc, 1);
      if (!h) m_[1][r] = tanhf(acc);
    }
    __syncthreads();

    // ---- agg last + mask select -> xv ----
    if (tid < 256) {
      const int r = tid >> 1, h = tid & 1;
      float acc = h ? 0.f : b_last[r];
      const unsigned* A = aggL + 16384;
      #pragma unroll 4
      for (int e2g = h*16; e2g < h*16+16; ++e2g) {
        float4 x = ((const float4*)m_[1])[e2g];
        uint2 u = *(const uint2*)(A + e2g*256 + r*2);
        acc += uflo(u.x)*x.x + ufhi(u.x)*x.y + uflo(u.y)*x.z + ufhi(u.y)*x.w;
      }
      acc += __shfl_xor(acc, 1);
      if (!h) xv[r] = smk[t] ? tanhf(acc) : e0[r];
    }
    __syncthreads();

    // ---- GRU1: streamed ih1a + hh1, 2 threads/row (384 rows) ----
    {
      float acc_i = hf ? 0.f : (b_ih1[r2] + gicorr[scc[t]][r2]);
      float acc_h = hf ? 0.f : b_hh1[r2];
      #pragma unroll 4
      for (int k = 0; k < 8; ++k) {
        uint4 u = Wi1[k*768 + tid];
        DOT8(u, xv2, hf*32 + k*4, acc_i);
      }
      #pragma unroll 4
      for (int k = 0; k < 8; ++k) {
        uint4 u = Wh1[k*768 + tid];
        DOT8(u, h12, hf*32 + k*4, acc_h);
      }
      acc_i += __shfl_xor(acc_i, 1);
      acc_h += __shfl_xor(acc_h, 1);
      if (!hf) { gi[r2] = acc_i; gh[r2] = acc_h; }
    }
    __syncthreads();
    if (tid < D) {
      float rg = 1.f/(1.f + expf(-(gi[tid]+gh[tid])));
      float zg = 1.f/(1.f + expf(-(gi[D+tid]+gh[D+tid])));
      float ng = tanhf(gi[2*D+tid] + rg*gh[2*D+tid]);
      h1[tid] = (1.f-zg)*ng + zg*h1[tid];
    }
    __syncthreads();

    // ---- GRU2: register-pinned weights (zero L2 traffic) ----
    {
      float acc_i = hf ? 0.f : b_ih2[r2];
      float acc_h = hf ? 0.f : b_hh2[r2];
      #pragma unroll
      for (int k = 0; k < 8; ++k) {
        DOT8(pwi[k], h12, hf*32 + k*4, acc_i);
        DOT8(pwh[k], h22, hf*32 + k*4, acc_h);
      }
      acc_i += __shfl_xor(acc_i, 1);
      acc_h += __shfl_xor(acc_h, 1);
      if (!hf) { gi[r2] = acc_i; gh[r2] = acc_h; }
    }
    __syncthreads();
    if (tid < D) {
      float rg = 1.f/(1.f + expf(-(gi[tid]+gh[tid])));
      float zg = 1.f/(1.f + expf(-(gi[D+tid]+gh[D+tid])));
      float ng = tanhf(gi[2*D+tid] + rg*gh[2*D+tid]);
      g2[tid] = (1.f-zg)*ng + zg*h2[tid];
    }
    __syncthreads();

    // ---- phase A: qry matvec (tids 0..255) | state update (256..383) | og dots (512..687) ----
    {
      float kep = 0.f;
      if (tid < 256) {
        const int r = tid >> 1, h = tid & 1;
        float acc = h ? 0.f : b_query[r];
        #pragma unroll 4
        for (int k = 0; k < 8; ++k) {
          uint4 u = Wq[k*256 + tid];
          DOT8(u, g22, h*32 + k*4, acc);
        }
        acc += __shfl_xor(acc, 1);
        if (!h) kep = tanhf(acc) * w_k[r];
      } else if (tid < 384) {
        const int d = tid - 256;
        if (t >= 1) { hist[t][d] = g2[d]; h2[d] = g2[d]; }
      } else if (tid >= 512 && tid < 688) {
        const int g = (tid - 512) >> 4, lane = tid & 15;
        const int ne = (t < RK ? t : RK) + 1;
        if (g < ne) {
          const float* row;
          if (g == 0) row = g2;
          else {
            int s = (t <= RK) ? (g-1) : idxk[t][g-1];
            row = hist[s];
            if (lane == 0) kwv[g] = kwh[s];
          }
          float part = 0.f;
          #pragma unroll
          for (int k = 0; k < 8; ++k) { int d = lane + (k<<4); part += qcs[d]*row[d]; }
          part += __shfl_xor(part, 8, 16);
          part += __shfl_xor(part, 4, 16);
          part += __shfl_xor(part, 2, 16);
          part += __shfl_xor(part, 1, 16);
          if (lane == 0) ogv[g] = part;
        }
      }
      #pragma unroll
      for (int off = 32; off; off >>= 1) kep += __shfl_down(kep, off);
      if ((tid & 63) == 0) red[tid >> 6] = kep;
    }
    __syncthreads();
  }

  // finalize step 62 -> y[:,63]
  if (tid == 0) {
    const int tp = SS - 2;  // 62
    const int ne = RK + 1;
    float cur = red[0]+red[1]+red[2]+red[3];
    kwv[0] = cur;
    float mx = kwv[0];
    for (int i2 = 1; i2 < ne; ++i2) mx = fmaxf(mx, kwv[i2]);
    float den = 0.f, num = 0.f;
    for (int i2 = 0; i2 < ne; ++i2) { float e_ = expf(kwv[i2]-mx); den += e_; num += e_*ogv[i2]; }
    float val = num/den;
    y[b*SS + tp + 1] = 1.f/(1.f + expf(-val));
  }
}

extern "C" void kernel_launch(void* const* d_in, const int* in_sizes, int n_in,
                              void* d_out, int out_size, void* d_ws, size_t ws_size,
                              hipStream_t stream)
{
  (void)in_sizes; (void)n_in; (void)out_size; (void)ws_size;

  const float* embQ  = (const float*)d_in[0];
  const float* embC  = (const float*)d_in[1];
  const float* embR  = (const float*)d_in[2];
  const float* Wih1  = (const float*)d_in[3];
  const float* Whh1  = (const float*)d_in[4];
  const float* bih1  = (const float*)d_in[5];
  const float* bhh1  = (const float*)d_in[6];
  const float* Wih2  = (const float*)d_in[7];
  const float* Whh2  = (const float*)d_in[8];
  const float* bih2  = (const float*)d_in[9];
  const float* bhh2  = (const float*)d_in[10];
  const float* Wagg  = (const float*)d_in[11];
  const float* bagg  = (const float*)d_in[12];
  const float* Wlast = (const float*)d_in[13];
  const float* blast = (const float*)d_in[14];
  const float* Wqry  = (const float*)d_in[15];
  const float* bqry  = (const float*)d_in[16];
  // d_in[17] W_key, [18] b_key, [19] w_q, [21] b_w cancel in the softmax -> unused
  const float* wk    = (const float*)d_in[20];
  const float* h1i   = (const float*)d_in[22];
  const float* h2i   = (const float*)d_in[23];
  const int* qnbr    = (const int*)d_in[24];
  const int* cnbr    = (const int*)d_in[25];
  const int* q2c     = (const int*)d_in[26];
  const int* qseq    = (const int*)d_in[27];
  const int* cseq    = (const int*)d_in[28];
  const int* mseq    = (const int*)d_in[29];

  unsigned* wsU = (unsigned*)d_ws;
  float* y = (float*)d_out;

  gikt_pack<<<(TOTAL_U + 255) / 256, 256, 0, stream>>>(Wih1, Whh1, Wih2, Whh2, Wagg, Wlast, Wqry, wsU);
  gikt_main<<<BB, T, 0, stream>>>(embQ, embC, embR, bih1, bhh1, bih2, bhh2, bagg, blast, bqry,
                                  wk, h1i, h2i, qnbr, cnbr, q2c, qseq, cseq, mseq, wsU, y);
}

// Round 4
// 1043.938 us; speedup vs baseline: 1.6933x; 1.0822x over previous
//
#include <hip/hip_runtime.h>
#include <math.h>

#define D    128
#define QN   4
#define CN   4
#define MAXC 4
#define BB   128
#define SS   64
#define RK   10
#define T    768   // 12 waves

// ---- packed-bf16 weight workspace layout (uint32 units; each uint = 2 bf16) ----
#define UOFF_IH1A 0        // cols 0..127 of W_ih1, chunked NT=768 K=8 -> 24576 uints
#define UOFF_IH1B 24576    // cols 128..255 of W_ih1: [e2l][384] -> 24576
#define UOFF_HH1  49152    // chunked NT=768 K=8 -> 24576
#define UOFF_IH2  73728    // chunked NT=768 K=8 (register-pinned) -> 24576
#define UOFF_HH2  98304    // chunked NT=768 K=8 (register-pinned) -> 24576
#define UOFF_QRY  122880   // [k][128] uint4, K=16 (1 thread/row) -> 8192
#define UOFF_A0   131072   // [e2g][2][128] -> 8192
#define UOFF_A1   139264   // -> 8192
#define UOFF_LS   147456   // -> 8192
#define TOTAL_U   155648

__device__ __forceinline__ unsigned bf1(float x){
  unsigned u = __float_as_uint(x);
  return (u + 0x7fffu + ((u >> 16) & 1u)) >> 16;   // RNE fp32->bf16
}
__device__ __forceinline__ float uflo(unsigned u){ return __uint_as_float(u << 16); }
__device__ __forceinline__ float ufhi(unsigned u){ return __uint_as_float(u & 0xffff0000u); }

__global__ void gikt_pack(const float* __restrict__ Wih1,
                          const float* __restrict__ Whh1,
                          const float* __restrict__ Wih2,
                          const float* __restrict__ Whh2,
                          const float* __restrict__ Wagg,
                          const float* __restrict__ Wlast,
                          const float* __restrict__ Wqry,
                          unsigned* __restrict__ wsU)
{
  int i = blockIdx.x * blockDim.x + threadIdx.x;
  if (i >= TOTAL_U) return;
  const float* src = nullptr; int row = 0, e2 = 0, stride = 0;
  int j = i;
  if (j < 24576) {               // ih1a: chunked, e2 = hf*32 + k*4 + c (cols 0..127)
    int c = j & 3, i4 = j >> 2, k = i4 / 768, t = i4 - k * 768, r = t >> 1, hf = t & 1;
    e2 = hf * 32 + k * 4 + c; row = r; src = Wih1; stride = 256;
  } else if ((j -= 24576) < 24576) {   // ih1b: [e2l][384], cols 128..255
    e2 = 64 + (j / 384); row = j % 384; src = Wih1; stride = 256;
  } else if ((j -= 24576) < 24576) {   // hh1
    int c = j & 3, i4 = j >> 2, k = i4 / 768, t = i4 - k * 768, r = t >> 1, hf = t & 1;
    e2 = hf * 32 + k * 4 + c; row = r; src = Whh1; stride = 128;
  } else if ((j -= 24576) < 24576) {   // ih2
    int c = j & 3, i4 = j >> 2, k = i4 / 768, t = i4 - k * 768, r = t >> 1, hf = t & 1;
    e2 = hf * 32 + k * 4 + c; row = r; src = Wih2; stride = 128;
  } else if ((j -= 24576) < 24576) {   // hh2
    int c = j & 3, i4 = j >> 2, k = i4 / 768, t = i4 - k * 768, r = t >> 1, hf = t & 1;
    e2 = hf * 32 + k * 4 + c; row = r; src = Whh2; stride = 128;
  } else if ((j -= 24576) < 8192) {    // qry: [k][128] uint4, e2 = k*4 + c
    int c = j & 3, i4 = j >> 2, k = i4 >> 7, r = i4 & 127;
    e2 = k * 4 + c; row = r; src = Wqry; stride = 128;
  } else if ((j -= 8192) < 8192) {     // a0: [e2g][2][128]
    int r = j & 127, p = (j >> 7) & 1, e2g = j >> 8;
    e2 = 2 * e2g + p; row = r; src = Wagg; stride = 128;
  } else if ((j -= 8192) < 8192) {     // a1
    int r = j & 127, p = (j >> 7) & 1, e2g = j >> 8;
    e2 = 2 * e2g + p; row = r; src = Wagg + 128 * 128; stride = 128;
  } else {                              // ls
    j -= 8192;
    int r = j & 127, p = (j >> 7) & 1, e2g = j >> 8;
    e2 = 2 * e2g + p; row = r; src = Wlast; stride = 128;
  }
  float lo = src[row * stride + 2 * e2];
  float hi = src[row * stride + 2 * e2 + 1];
  wsU[i] = bf1(lo) | (bf1(hi) << 16);
}

#define DOT8(u4, xp, e2b, acc) {                                   \
  float2 x0=(xp)[(e2b)], x1=(xp)[(e2b)+1], x2=(xp)[(e2b)+2], x3=(xp)[(e2b)+3]; \
  acc += uflo(u4.x)*x0.x + ufhi(u4.x)*x0.y;                        \
  acc += uflo(u4.y)*x1.x + ufhi(u4.y)*x1.y;                        \
  acc += uflo(u4.z)*x2.x + ufhi(u4.z)*x2.y;                        \
  acc += uflo(u4.w)*x3.x + ufhi(u4.w)*x3.y; }

__launch_bounds__(T, 1)
__global__ void gikt_main(
    const float* __restrict__ embQ,
    const float* __restrict__ embC,
    const float* __restrict__ embR,
    const float* __restrict__ b_ih1,
    const float* __restrict__ b_hh1,
    const float* __restrict__ b_ih2,
    const float* __restrict__ b_hh2,
    const float* __restrict__ b_agg,
    const float* __restrict__ b_last,
    const float* __restrict__ b_query,
    const float* __restrict__ w_k,
    const float* __restrict__ h1i,
    const float* __restrict__ h2i,
    const int* __restrict__ qnbr,
    const int* __restrict__ cnbr,
    const int* __restrict__ q2c,
    const int* __restrict__ qseq,
    const int* __restrict__ cseq,
    const int* __restrict__ mseq,
    const unsigned* __restrict__ wsU,
    float* __restrict__ y)
{
  const int b   = blockIdx.x;
  const int tid = threadIdx.x;
  const int r2  = tid >> 1, hf = tid & 1;

  __shared__ unsigned aggL[3 * 8192];       // a0|a1|ls, [e2g][2][128]; phase0 alias: Gram
  __shared__ float hist[SS][129];           // phase0: E rows; loop: state history (row0 = zero)
  __shared__ float gicorr[2][384];
  __shared__ int   idxk[SS][RK];
  __shared__ float kwh[SS];
  __shared__ __align__(16) float m_[5][D];
  __shared__ __align__(16) float a_[5][D];
  __shared__ __align__(16) float xv[D];
  __shared__ float gi[3*D];
  __shared__ float gh[3*D];
  __shared__ __align__(16) float h1[D];
  __shared__ __align__(16) float h2[D];
  __shared__ __align__(16) float g2prev[D];
  __shared__ float e0[D];
  __shared__ __align__(16) float qcs[2][D]; // double-buffered (predict is deferred 1 step)
  __shared__ float kevec[D];
  __shared__ int   sq[SS], scc[SS], smk[SS];
  __shared__ int   nn1[SS][QN], nn2[SS][QN*CN], cc2[SS][MAXC];
  __shared__ float red[12];
  __shared__ float ogv[16], kwv[16];

  float (*G)[65] = (float(*)[65])aggL;

  // ---- pinned GRU2 weights: 16 uint4 ----
  uint4 pwi[8], pwh[8];
  {
    const uint4* Pi = (const uint4*)(wsU + UOFF_IH2);
    const uint4* Ph = (const uint4*)(wsU + UOFF_HH2);
    #pragma unroll
    for (int k = 0; k < 8; ++k) { pwi[k] = Pi[k*768 + tid]; pwh[k] = Ph[k*768 + tid]; }
  }

  // ---- phase 0a: sequences ----
  for (int i = tid; i < SS; i += T) { sq[i]=qseq[b*SS+i]; scc[i]=cseq[b*SS+i]; smk[i]=mseq[b*SS+i]; }
  __syncthreads();

  // ---- phase 0b: E rows into hist; 1-hop indices ----
  for (int i = tid; i < SS*32; i += T) {
    int s = i >> 5, e4 = i & 31;
    float4 v = ((const float4*)(embQ + sq[s]*D))[e4];
    hist[s][e4*4+0] = v.x; hist[s][e4*4+1] = v.y; hist[s][e4*4+2] = v.z; hist[s][e4*4+3] = v.w;
  }
  for (int i = tid; i < (SS-1)*QN; i += T)   { int t = i>>2, j = i&3; nn1[t][j] = qnbr[sq[t]*QN + j]; }
  for (int i = tid; i < (SS-1)*MAXC; i += T) { int t = i>>2, j = i&3; cc2[t][j] = q2c[sq[t+1]*MAXC + j]; }
  __syncthreads();

  // ---- phase 0c: Gram (fp32), 2-hop indices, gicorr ----
  for (int p = tid; p < SS*SS; p += T) {
    int tq = p >> 6, s = p & 63;
    if (tq >= RK+2 && s < tq-1) {
      float acc = 0.f;
      #pragma unroll 8
      for (int d = 0; d < D; ++d) acc += hist[tq][d]*hist[s][d];
      G[tq-(RK+2)][s] = acc;
    }
  }
  for (int i = tid; i < (SS-1)*QN*CN; i += T) {
    int t = i>>4, j = (i>>2)&3, l = i&3;
    nn2[t][j*CN+l] = cnbr[nn1[t][j]*CN + l];
  }
  {
    const int c = (tid >= 384) ? 1 : 0, r = tid - (c ? 384 : 0);
    const float2* er2 = (const float2*)(embR + c*D);
    float acc = 0.f;
    #pragma unroll 4
    for (int e2l = 0; e2l < 64; ++e2l) {
      unsigned u = wsU[UOFF_IH1B + e2l*384 + r];
      float2 x = er2[e2l];
      acc += uflo(u)*x.x + ufhi(u)*x.y;
    }
    gicorr[c][r] = acc;
  }
  __syncthreads();

  // ---- phase 0d: stable top-k ----
  if (tid < 52) {
    int t = RK + 1 + tid;
    for (int k = 0; k < RK; ++k) {
      float best = -INFINITY; int bi = 0;
      for (int s = 0; s < t; ++s) { float v = G[tid][s]; if (v > best) { best = v; bi = s; } }
      idxk[t][k] = bi;
      G[tid][bi] = -INFINITY;
    }
  }
  __syncthreads();

  // ---- phase 0e: agg weights into LDS; state init; kw(zero-state) ----
  for (int i = tid; i < 3*8192; i += T) aggL[i] = wsU[UOFF_A0 + i];
  if (tid < D) { hist[0][tid] = 0.f; h1[tid] = h1i[b*D+tid]; h2[tid] = h2i[b*D+tid]; g2prev[tid] = 0.f; }
  if (tid == 0) y[b*SS + 1] = 0.f;   // never written by reference
  {
    float p0 = (tid < D) ? w_k[tid]*tanhf(b_query[tid]) : 0.f;
    #pragma unroll
    for (int off = 32; off; off >>= 1) p0 += __shfl_down(p0, off);
    if ((tid & 63) == 0) red[tid >> 6] = p0;
  }
  __syncthreads();
  if (tid == 0) kwh[0] = red[0]+red[1];
  __syncthreads();

  const uint4* Wi1 = (const uint4*)(wsU + UOFF_IH1A);
  const uint4* Wh1 = (const uint4*)(wsU + UOFF_HH1);
  const uint4* Wq4 = (const uint4*)(wsU + UOFF_QRY);
  const float2* h12 = (const float2*)h1;
  const float2* h22 = (const float2*)h2;
  const float2* xv2 = (const float2*)xv;
  const float2* gp2 = (const float2*)g2prev;

  // ---- sequential time loop: step t computes GRU(t); predict(t-1) runs in P2-P4 ----
  for (int t = 0; t < SS-1; ++t) {
    const int tp = t - 1;

    // ---- P1: gather (6 groups of 128) ----
    {
      const int d   = tid & 127;
      const int grp = tid >> 7;
      if (grp == 0) {
        float ev = embQ[sq[t]*D + d];
        e0[d] = ev;
        float s1 = embC[nn1[t][0]*D+d]+embC[nn1[t][1]*D+d]+embC[nn1[t][2]*D+d]+embC[nn1[t][3]*D+d];
        m_[0][d] = ev + 0.25f*s1;
      } else if (grp <= 4) {
        const int j = grp - 1;
        float e1v = embC[nn1[t][j]*D + d];
        float s2  = embQ[nn2[t][j*CN+0]*D+d]+embQ[nn2[t][j*CN+1]*D+d]
                   +embQ[nn2[t][j*CN+2]*D+d]+embQ[nn2[t][j*CN+3]*D+d];
        m_[grp][d] = e1v + 0.25f*s2;
      } else {
        float acc = embQ[sq[t+1]*D + d];
        #pragma unroll
        for (int mm = 0; mm < MAXC; ++mm) acc += embC[cc2[t][mm]*D + d];
        qcs[t & 1][d] = acc;
      }
    }
    __syncthreads();

    // ---- P2: agg1 (0..639) | qry on g2prev (640..767, 1 thread/row) ----
    if (tid < 640) {
      const int which = tid >> 7, r = tid & 127;
      const unsigned* A = aggL + (which ? 8192 : 0);
      const float4* x4p = (const float4*)m_[which];
      float acc = (which == 0) ? b_agg[r] : b_agg[D + r];
      #pragma unroll 8
      for (int e2g = 0; e2g < 32; ++e2g) {
        unsigned u0 = A[e2g*256 + r];
        unsigned u1 = A[e2g*256 + 128 + r];
        float4 x = x4p[e2g];
        acc += uflo(u0)*x.x + ufhi(u0)*x.y + uflo(u1)*x.z + ufhi(u1)*x.w;
      }
      a_[which][r] = tanhf(acc);
    } else {
      const int r = tid - 640;
      float acc = b_query[r];
      #pragma unroll 8
      for (int k = 0; k < 16; ++k) {
        uint4 u = Wq4[k*128 + r];
        DOT8(u, gp2, k*4, acc);
      }
      kevec[r] = tanhf(acc) * w_k[r];
    }
    __syncthreads();

    // ---- P3: agg2 (0..255) | og-prev (256..431) | kw-reduce (512..575) ----
    if (tid < 256) {
      const int r = tid >> 1, h = tid & 1;
      float acc = h ? 0.f : b_agg[r];
      #pragma unroll 4
      for (int e2g = h*16; e2g < h*16+16; ++e2g) {
        float4 a0v = ((const float4*)a_[0])[e2g];
        float4 a1v = ((const float4*)a_[1])[e2g];
        float4 a2v = ((const float4*)a_[2])[e2g];
        float4 a3v = ((const float4*)a_[3])[e2g];
        float4 a4v = ((const float4*)a_[4])[e2g];
        float4 x; x.x = a0v.x + 0.25f*(a1v.x+a2v.x+a3v.x+a4v.x);
                  x.y = a0v.y + 0.25f*(a1v.y+a2v.y+a3v.y+a4v.y);
                  x.z = a0v.z + 0.25f*(a1v.z+a2v.z+a3v.z+a4v.z);
                  x.w = a0v.w + 0.25f*(a1v.w+a2v.w+a3v.w+a4v.w);
        unsigned u0 = aggL[e2g*256 + r];
        unsigned u1 = aggL[e2g*256 + 128 + r];
        acc += uflo(u0)*x.x + ufhi(u0)*x.y + uflo(u1)*x.z + ufhi(u1)*x.w;
      }
      acc += __shfl_xor(acc, 1);
      if (!h) m_[1][r] = tanhf(acc);
    } else if (tid >= 256 && tid < 432 && t >= 1) {
      const int g = (tid - 256) >> 4, lane = tid & 15;
      const int ne = (tp < RK ? tp : RK) + 1;
      if (g < ne) {
        const float* row;
        if (g == 0) row = g2prev;
        else {
          int s = (tp <= RK) ? (g-1) : idxk[tp][g-1];
          row = hist[s];
          if (lane == 0) kwv[g] = kwh[s];
        }
        const float* qp = qcs[tp & 1];
        float part = 0.f;
        #pragma unroll
        for (int k = 0; k < 8; ++k) { int d = lane + (k<<4); part += qp[d]*row[d]; }
        part += __shfl_xor(part, 8, 16);
        part += __shfl_xor(part, 4, 16);
        part += __shfl_xor(part, 2, 16);
        part += __shfl_xor(part, 1, 16);
        if (lane == 0) ogv[g] = part;
      }
    } else if (tid >= 512 && tid < 576 && t >= 1) {
      const int lane = tid & 63;
      float v = kevec[lane] + kevec[lane + 64];
      #pragma unroll
      for (int off = 32; off; off >>= 1) v += __shfl_down(v, off);
      if (lane == 0) { kwv[0] = v; if (tp >= 1) kwh[tp] = v; }
    }
    __syncthreads();

    // ---- P4: ls -> xv (0..255) | y-finalize prev (tid 256) ----
    if (tid < 256) {
      const int r = tid >> 1, h = tid & 1;
      float acc = h ? 0.f : b_last[r];
      const unsigned* A = aggL + 16384;
      #pragma unroll 4
      for (int e2g = h*16; e2g < h*16+16; ++e2g) {
        float4 x = ((const float4*)m_[1])[e2g];
        unsigned u0 = A[e2g*256 + r];
        unsigned u1 = A[e2g*256 + 128 + r];
        acc += uflo(u0)*x.x + ufhi(u0)*x.y + uflo(u1)*x.z + ufhi(u1)*x.w;
      }
      acc += __shfl_xor(acc, 1);
      if (!h) xv[r] = smk[t] ? tanhf(acc) : e0[r];
    } else if (tid == 256 && t >= 1) {
      const int ne = (tp < RK ? tp : RK) + 1;
      float mx = kwv[0];
      for (int i2 = 1; i2 < ne; ++i2) mx = fmaxf(mx, kwv[i2]);
      float den = 0.f, num = 0.f;
      for (int i2 = 0; i2 < ne; ++i2) { float e_ = expf(kwv[i2]-mx); den += e_; num += e_*ogv[i2]; }
      float val = num/den;
      y[b*SS + ((tp==0) ? 0 : (tp+1))] = 1.f/(1.f + expf(-val));
    }
    __syncthreads();

    // ---- P5: GRU1 (2 threads/row) ----
    {
      float acc_i = hf ? 0.f : (b_ih1[r2] + gicorr[scc[t]][r2]);
      float acc_h = hf ? 0.f : b_hh1[r2];
      #pragma unroll 4
      for (int k = 0; k < 8; ++k) {
        uint4 u = Wi1[k*768 + tid];
        DOT8(u, xv2, hf*32 + k*4, acc_i);
      }
      #pragma unroll 4
      for (int k = 0; k < 8; ++k) {
        uint4 u = Wh1[k*768 + tid];
        DOT8(u, h12, hf*32 + k*4, acc_h);
      }
      acc_i += __shfl_xor(acc_i, 1);
      acc_h += __shfl_xor(acc_h, 1);
      if (!hf) { gi[r2] = acc_i; gh[r2] = acc_h; }
    }
    __syncthreads();

    // ---- P6: GRU1 nonlinearity ----
    if (tid < D) {
      float rg = 1.f/(1.f + expf(-(gi[tid]+gh[tid])));
      float zg = 1.f/(1.f + expf(-(gi[D+tid]+gh[D+tid])));
      float ng = tanhf(gi[2*D+tid] + rg*gh[2*D+tid]);
      h1[tid] = (1.f-zg)*ng + zg*h1[tid];
    }
    __syncthreads();

    // ---- P7: GRU2 (register-pinned weights) ----
    {
      float acc_i = hf ? 0.f : b_ih2[r2];
      float acc_h = hf ? 0.f : b_hh2[r2];
      #pragma unroll
      for (int k = 0; k < 8; ++k) {
        DOT8(pwi[k], h12, hf*32 + k*4, acc_i);
        DOT8(pwh[k], h22, hf*32 + k*4, acc_h);
      }
      acc_i += __shfl_xor(acc_i, 1);
      acc_h += __shfl_xor(acc_h, 1);
      if (!hf) { gi[r2] = acc_i; gh[r2] = acc_h; }
    }
    __syncthreads();

    // ---- P8: GRU2 nonlinearity + state updates ----
    if (tid < D) {
      float rg = 1.f/(1.f + expf(-(gi[tid]+gh[tid])));
      float zg = 1.f/(1.f + expf(-(gi[D+tid]+gh[D+tid])));
      float ng = tanhf(gi[2*D+tid] + rg*gh[2*D+tid]);
      float g2v = (1.f-zg)*ng + zg*h2[tid];
      g2prev[tid] = g2v;
      if (t >= 1) { h2[tid] = g2v; hist[t][tid] = g2v; }   // t==0: reference skips update
    }
    __syncthreads();
  }

  // ---- epilogue: predict for tp = 62 ----
  {
    const int tp = SS - 2;
    if (tid < 128) {
      const int r = tid;
      float acc = b_query[r];
      #pragma unroll 8
      for (int k = 0; k < 16; ++k) {
        uint4 u = Wq4[k*128 + r];
        DOT8(u, gp2, k*4, acc);
      }
      kevec[r] = tanhf(acc) * w_k[r];
    }
    __syncthreads();
    if (tid < 176) {
      const int g = tid >> 4, lane = tid & 15;
      const int ne = RK + 1;
      if (g < ne) {
        const float* row;
        if (g == 0) row = g2prev;
        else {
          int s = idxk[tp][g-1];
          row = hist[s];
          if (lane == 0) kwv[g] = kwh[s];
        }
        const float* qp = qcs[tp & 1];
        float part = 0.f;
        #pragma unroll
        for (int k = 0; k < 8; ++k) { int d = lane + (k<<4); part += qp[d]*row[d]; }
        part += __shfl_xor(part, 8, 16);
        part += __shfl_xor(part, 4, 16);
        part += __shfl_xor(part, 2, 16);
        part += __shfl_xor(part, 1, 16);
        if (lane == 0) ogv[g] = part;
      }
    } else if (tid >= 256 && tid < 320) {
      const int lane = tid & 63;
      float v = kevec[lane] + kevec[lane + 64];
      #pragma unroll
      for (int off = 32; off; off >>= 1) v += __shfl_down(v, off);
      if (lane == 0) kwv[0] = v;
    }
    __syncthreads();
    if (tid == 0) {
      const int ne = RK + 1;
      float mx = kwv[0];
      for (int i2 = 1; i2 < ne; ++i2) mx = fmaxf(mx, kwv[i2]);
      float den = 0.f, num = 0.f;
      for (int i2 = 0; i2 < ne; ++i2) { float e_ = expf(kwv[i2]-mx); den += e_; num += e_*ogv[i2]; }
      float val = num/den;
      y[b*SS + tp + 1] = 1.f/(1.f + expf(-val));
    }
  }
}

extern "C" void kernel_launch(void* const* d_in, const int* in_sizes, int n_in,
                              void* d_out, int out_size, void* d_ws, size_t ws_size,
                              hipStream_t stream)
{
  (void)in_sizes; (void)n_in; (void)out_size; (void)ws_size;

  const float* embQ  = (const float*)d_in[0];
  const float* embC  = (const float*)d_in[1];
  const float* embR  = (const float*)d_in[2];
  const float* Wih1  = (const float*)d_in[3];
  const float* Whh1  = (const float*)d_in[4];
  const float* bih1  = (const float*)d_in[5];
  const float* bhh1  = (const float*)d_in[6];
  const float* Wih2  = (const float*)d_in[7];
  const float* Whh2  = (const float*)d_in[8];
  const float* bih2  = (const float*)d_in[9];
  const float* bhh2  = (const float*)d_in[10];
  const float* Wagg  = (const float*)d_in[11];
  const float* bagg  = (const float*)d_in[12];
  const float* Wlast = (const float*)d_in[13];
  const float* blast = (const float*)d_in[14];
  const float* Wqry  = (const float*)d_in[15];
  const float* bqry  = (const float*)d_in[16];
  // d_in[17] W_key, [18] b_key, [19] w_q, [21] b_w cancel in the softmax -> unused
  const float* wk    = (const float*)d_in[20];
  const float* h1i   = (const float*)d_in[22];
  const float* h2i   = (const float*)d_in[23];
  const int* qnbr    = (const int*)d_in[24];
  const int* cnbr    = (const int*)d_in[25];
  const int* q2c     = (const int*)d_in[26];
  const int* qseq    = (const int*)d_in[27];
  const int* cseq    = (const int*)d_in[28];
  const int* mseq    = (const int*)d_in[29];

  unsigned* wsU = (unsigned*)d_ws;
  float* y = (float*)d_out;

  gikt_pack<<<(TOTAL_U + 255) / 256, 256, 0, stream>>>(Wih1, Whh1, Wih2, Whh2, Wagg, Wlast, Wqry, wsU);
  gikt_main<<<BB, T, 0, stream>>>(embQ, embC, embR, bih1, bhh1, bih2, bhh2, bagg, blast, bqry,
                                  wk, h1i, h2i, qnbr, cnbr, q2c, qseq, cseq, mseq, wsU, y);
}

// Round 5
// 774.952 us; speedup vs baseline: 2.2810x; 1.3471x over previous
//
#include <hip/hip_runtime.h>
#include <math.h>

#define D    128
#define QN   4
#define CN   4
#define MAXC 4
#define BB   128
#define SS   64
#define RK   10
#define T    768   // 12 waves

// ---- packed-fp16 weight workspace layout (uint32 units; each uint = 2 half) ----
#define UOFF_IH1A 0        // cols 0..127 of W_ih1, chunked NT=768 K=8 -> 24576 uints
#define UOFF_IH1B 24576    // cols 128..255 of W_ih1: [e2l][384] -> 24576
#define UOFF_HH1  49152    // chunked NT=768 K=8 -> 24576
#define UOFF_IH2  73728    // chunked NT=768 K=8 (register-pinned) -> 24576
#define UOFF_HH2  98304    // chunked NT=768 K=8 (register-pinned) -> 24576
#define UOFF_QRY  122880   // [k][128] uint4, K=16 (1 thread/row) -> 8192
#define UOFF_A0   131072   // [e2g][2][128] -> 8192
#define UOFF_A1   139264   // -> 8192
#define UOFF_LS   147456   // -> 8192
#define TOTAL_U   155648

typedef _Float16 h2_t __attribute__((ext_vector_type(2)));
union U32H2 { unsigned u; h2_t h; unsigned short s2[2]; };

__device__ __forceinline__ unsigned h16f(float x){
  U32H2 c; c.h[0] = (_Float16)x; c.h[1] = (_Float16)0.f;
  return (unsigned)c.s2[0];
}
__device__ __forceinline__ unsigned packh2(float a, float b){
  U32H2 c; c.h[0] = (_Float16)a; c.h[1] = (_Float16)b;
  return c.u;
}
__device__ __forceinline__ float dot2(unsigned w, unsigned x, float acc){
  U32H2 a; a.u = w; U32H2 b; b.u = x;
  return __builtin_amdgcn_fdot2(a.h, b.h, acc, false);
}
__device__ __forceinline__ float hlo(unsigned u){ U32H2 a; a.u=u; return (float)a.h[0]; }
__device__ __forceinline__ float hhi(unsigned u){ U32H2 a; a.u=u; return (float)a.h[1]; }

#define FD4(w4, x4, acc) { \
  acc = dot2((w4).x, (x4).x, acc); acc = dot2((w4).y, (x4).y, acc); \
  acc = dot2((w4).z, (x4).z, acc); acc = dot2((w4).w, (x4).w, acc); }

__global__ void gikt_pack(const float* __restrict__ Wih1,
                          const float* __restrict__ Whh1,
                          const float* __restrict__ Wih2,
                          const float* __restrict__ Whh2,
                          const float* __restrict__ Wagg,
                          const float* __restrict__ Wlast,
                          const float* __restrict__ Wqry,
                          unsigned* __restrict__ wsU)
{
  int i = blockIdx.x * blockDim.x + threadIdx.x;
  if (i >= TOTAL_U) return;
  const float* src = nullptr; int row = 0, e2 = 0, stride = 0;
  int j = i;
  if (j < 24576) {               // ih1a
    int c = j & 3, i4 = j >> 2, k = i4 / 768, t = i4 - k * 768, r = t >> 1, hf = t & 1;
    e2 = hf * 32 + k * 4 + c; row = r; src = Wih1; stride = 256;
  } else if ((j -= 24576) < 24576) {   // ih1b
    e2 = 64 + (j / 384); row = j % 384; src = Wih1; stride = 256;
  } else if ((j -= 24576) < 24576) {   // hh1
    int c = j & 3, i4 = j >> 2, k = i4 / 768, t = i4 - k * 768, r = t >> 1, hf = t & 1;
    e2 = hf * 32 + k * 4 + c; row = r; src = Whh1; stride = 128;
  } else if ((j -= 24576) < 24576) {   // ih2
    int c = j & 3, i4 = j >> 2, k = i4 / 768, t = i4 - k * 768, r = t >> 1, hf = t & 1;
    e2 = hf * 32 + k * 4 + c; row = r; src = Wih2; stride = 128;
  } else if ((j -= 24576) < 24576) {   // hh2
    int c = j & 3, i4 = j >> 2, k = i4 / 768, t = i4 - k * 768, r = t >> 1, hf = t & 1;
    e2 = hf * 32 + k * 4 + c; row = r; src = Whh2; stride = 128;
  } else if ((j -= 24576) < 8192) {    // qry
    int c = j & 3, i4 = j >> 2, k = i4 >> 7, r = i4 & 127;
    e2 = k * 4 + c; row = r; src = Wqry; stride = 128;
  } else if ((j -= 8192) < 8192) {     // a0
    int r = j & 127, p = (j >> 7) & 1, e2g = j >> 8;
    e2 = 2 * e2g + p; row = r; src = Wagg; stride = 128;
  } else if ((j -= 8192) < 8192) {     // a1
    int r = j & 127, p = (j >> 7) & 1, e2g = j >> 8;
    e2 = 2 * e2g + p; row = r; src = Wagg + 128 * 128; stride = 128;
  } else {                              // ls
    j -= 8192;
    int r = j & 127, p = (j >> 7) & 1, e2g = j >> 8;
    e2 = 2 * e2g + p; row = r; src = Wlast; stride = 128;
  }
  float lo = src[row * stride + 2 * e2];
  float hi = src[row * stride + 2 * e2 + 1];
  wsU[i] = h16f(lo) | (h16f(hi) << 16);
}

__device__ __forceinline__ float2 gru_nl2(float2 gr, float2 gz, float2 gn,
                                          float2 hr, float2 hz, float2 hn,
                                          float2 hold){
  float2 out;
  {
    float rg = 1.f/(1.f + expf(-(gr.x + hr.x)));
    float zg = 1.f/(1.f + expf(-(gz.x + hz.x)));
    float ng = tanhf(gn.x + rg*hn.x);
    out.x = (1.f-zg)*ng + zg*hold.x;
  }
  {
    float rg = 1.f/(1.f + expf(-(gr.y + hr.y)));
    float zg = 1.f/(1.f + expf(-(gz.y + hz.y)));
    float ng = tanhf(gn.y + rg*hn.y);
    out.y = (1.f-zg)*ng + zg*hold.y;
  }
  return out;
}

__launch_bounds__(T, 1)
__global__ void gikt_main(
    const float* __restrict__ embQ,
    const float* __restrict__ embC,
    const float* __restrict__ embR,
    const float* __restrict__ b_ih1,
    const float* __restrict__ b_hh1,
    const float* __restrict__ b_ih2,
    const float* __restrict__ b_hh2,
    const float* __restrict__ b_agg,
    const float* __restrict__ b_last,
    const float* __restrict__ b_query,
    const float* __restrict__ w_k,
    const float* __restrict__ h1i,
    const float* __restrict__ h2i,
    const int* __restrict__ qnbr,
    const int* __restrict__ cnbr,
    const int* __restrict__ q2c,
    const int* __restrict__ qseq,
    const int* __restrict__ cseq,
    const int* __restrict__ mseq,
    const unsigned* __restrict__ wsU,
    float* __restrict__ y)
{
  const int b   = blockIdx.x;
  const int tid = threadIdx.x;
  const int r2  = tid >> 1, hf = tid & 1;

  __shared__ unsigned aggL[3 * 8192];          // a0|a1|ls; phase0 alias: Gram
  __shared__ float hist[SS][129];              // state history fp32 (row0 = zero)
  __shared__ float gicorr[2][384];
  __shared__ int   idxk[SS][RK];
  __shared__ float kwh[SS];
  __shared__ __align__(16) float a_[5][D];
  __shared__ __align__(16) float gi1[3*D];
  __shared__ __align__(16) float gh1[3*D];
  __shared__ __align__(16) float gi2[3*D];
  __shared__ __align__(16) float gh2[3*D];
  __shared__ __align__(16) float h1fp[2][D];   // canonical fp32 h1 (dbuf)
  __shared__ __align__(16) float g2fp[2][D];   // canonical fp32 g2 (dbuf)
  __shared__ __align__(16) float h2ifp[D];
  __shared__ float e0[D];
  __shared__ __align__(16) float qcs[2][D];
  __shared__ float kevec[D];
  // fp16-packed matvec inputs (uint = 2 half)
  __shared__ __align__(16) unsigned mPu[5][64];
  __shared__ __align__(16) unsigned vPu[64];
  __shared__ __align__(16) unsigned m1Pu[64];
  __shared__ __align__(16) unsigned xvPu[64];
  __shared__ __align__(16) unsigned h1Pu[64];
  __shared__ __align__(16) unsigned g2Pu[64];
  __shared__ __align__(16) unsigned h2iPu[64];
  __shared__ int   sq[SS], scc[SS], smk[SS];
  __shared__ int   nn1[SS][QN], nn2[SS][QN*CN], cc2[SS][MAXC];
  __shared__ float red[12];
  __shared__ float ogv[16], kwv[16];

  float (*G)[65] = (float(*)[65])aggL;

  // ---- pinned GRU2 weights: 16 uint4 = 64 VGPRs ----
  uint4 pwi[8], pwh[8];
  {
    const uint4* Pi = (const uint4*)(wsU + UOFF_IH2);
    const uint4* Ph = (const uint4*)(wsU + UOFF_HH2);
    #pragma unroll
    for (int k = 0; k < 8; ++k) { pwi[k] = Pi[k*768 + tid]; pwh[k] = Ph[k*768 + tid]; }
  }

  // ---- phase 0a: sequences ----
  for (int i = tid; i < SS; i += T) { sq[i]=qseq[b*SS+i]; scc[i]=cseq[b*SS+i]; smk[i]=mseq[b*SS+i]; }
  __syncthreads();

  // ---- phase 0b: E rows into hist; 1-hop indices ----
  for (int i = tid; i < SS*32; i += T) {
    int s = i >> 5, e4 = i & 31;
    float4 v = ((const float4*)(embQ + sq[s]*D))[e4];
    hist[s][e4*4+0] = v.x; hist[s][e4*4+1] = v.y; hist[s][e4*4+2] = v.z; hist[s][e4*4+3] = v.w;
  }
  for (int i = tid; i < (SS-1)*QN; i += T)   { int t = i>>2, j = i&3; nn1[t][j] = qnbr[sq[t]*QN + j]; }
  for (int i = tid; i < (SS-1)*MAXC; i += T) { int t = i>>2, j = i&3; cc2[t][j] = q2c[sq[t+1]*MAXC + j]; }
  __syncthreads();

  // ---- phase 0c: Gram (fp32), 2-hop indices, gicorr ----
  for (int p = tid; p < SS*SS; p += T) {
    int tq = p >> 6, s = p & 63;
    if (tq >= RK+2 && s < tq-1) {
      float acc = 0.f;
      #pragma unroll 8
      for (int d = 0; d < D; ++d) acc += hist[tq][d]*hist[s][d];
      G[tq-(RK+2)][s] = acc;
    }
  }
  for (int i = tid; i < (SS-1)*QN*CN; i += T) {
    int t = i>>4, j = (i>>2)&3, l = i&3;
    nn2[t][j*CN+l] = cnbr[nn1[t][j]*CN + l];
  }
  {
    const int c = (tid >= 384) ? 1 : 0, r = tid - (c ? 384 : 0);
    const float2* er2 = (const float2*)(embR + c*D);
    float acc = 0.f;
    #pragma unroll 4
    for (int e2l = 0; e2l < 64; ++e2l) {
      unsigned u = wsU[UOFF_IH1B + e2l*384 + r];
      float2 x = er2[e2l];
      acc += hlo(u)*x.x + hhi(u)*x.y;
    }
    gicorr[c][r] = acc;
  }
  __syncthreads();

  // ---- phase 0d: stable top-k (ties -> lowest index, = jax.lax.top_k) ----
  if (tid < 52) {
    int t = RK + 1 + tid;
    for (int k = 0; k < RK; ++k) {
      float best = -INFINITY; int bi = 0;
      for (int s = 0; s < t; ++s) { float v = G[tid][s]; if (v > best) { best = v; bi = s; } }
      idxk[t][k] = bi;
      G[tid][bi] = -INFINITY;
    }
  }
  __syncthreads();

  // ---- phase 0e: agg weights into LDS (overwrites Gram); state init; kw(zero-state) ----
  for (int i = tid; i < 3*8192; i += T) aggL[i] = wsU[UOFF_A0 + i];
  if (tid < 64) {
    float a0 = h1i[b*D+2*tid], a1 = h1i[b*D+2*tid+1];
    h1Pu[tid] = packh2(a0, a1);
    ((float2*)h1fp[1])[tid] = make_float2(a0, a1);
    float c0 = h2i[b*D+2*tid], c1 = h2i[b*D+2*tid+1];
    h2iPu[tid] = packh2(c0, c1);
    ((float2*)h2ifp)[tid] = make_float2(c0, c1);
    g2Pu[tid] = 0;
  }
  if (tid < D) hist[0][tid] = 0.f;
  if (tid == 0) y[b*SS + 1] = 0.f;   // never written by reference
  {
    float p0 = (tid < D) ? w_k[tid]*tanhf(b_query[tid]) : 0.f;
    #pragma unroll
    for (int off = 32; off; off >>= 1) p0 += __shfl_down(p0, off);
    if ((tid & 63) == 0) red[tid >> 6] = p0;
  }
  __syncthreads();
  if (tid == 0) kwh[0] = red[0]+red[1];
  __syncthreads();

  const uint4* Wi1 = (const uint4*)(wsU + UOFF_IH1A);
  const uint4* Wh1 = (const uint4*)(wsU + UOFF_HH1);
  const uint4* Wq4 = (const uint4*)(wsU + UOFF_QRY);

  // ==== time loop: step t runs GRU(t); g2(t-1) finalizes in P1; predict(t-1) in P2-P4 ====
  for (int t = 0; t < SS-1; ++t) {
    const int tp = t - 1;

    // ---- P1: wave0 finalizes g2(t-1); all gather ----
    if (tid < 64 && t >= 1) {
      const int l = tid;
      const float* ph2 = (t <= 2) ? h2ifp : g2fp[t & 1];     // h2-state(t-1)
      float2 hold = ((const float2*)ph2)[l];
      float2 gv = gru_nl2(((const float2*)gi2)[l], ((const float2*)(gi2+128))[l], ((const float2*)(gi2+256))[l],
                          ((const float2*)gh2)[l], ((const float2*)(gh2+128))[l], ((const float2*)(gh2+256))[l],
                          hold);
      ((float2*)g2fp[(t+1)&1])[l] = gv;
      g2Pu[l] = packh2(gv.x, gv.y);
      if (t >= 2) { hist[t-1][2*l] = gv.x; hist[t-1][2*l+1] = gv.y; }
    }
    {
      const int d   = tid & 127;
      const int grp = tid >> 7;
      if (grp == 0) {
        float ev = embQ[sq[t]*D + d];
        e0[d] = ev;
        float s1 = embC[nn1[t][0]*D+d]+embC[nn1[t][1]*D+d]+embC[nn1[t][2]*D+d]+embC[nn1[t][3]*D+d];
        ((_Float16*)mPu[0])[d] = (_Float16)(ev + 0.25f*s1);
      } else if (grp <= 4) {
        const int j = grp - 1;
        float e1v = embC[nn1[t][j]*D + d];
        float s2  = embQ[nn2[t][j*CN+0]*D+d]+embQ[nn2[t][j*CN+1]*D+d]
                   +embQ[nn2[t][j*CN+2]*D+d]+embQ[nn2[t][j*CN+3]*D+d];
        ((_Float16*)mPu[grp])[d] = (_Float16)(e1v + 0.25f*s2);
      } else {
        float acc = embQ[sq[t+1]*D + d];
        #pragma unroll
        for (int mm = 0; mm < MAXC; ++mm) acc += embC[cc2[t][mm]*D + d];
        qcs[t & 1][d] = acc;
      }
    }
    __syncthreads();

    // ---- P2: agg1 (0..639) | qry on g2(t-1) (640..767) ----
    if (tid < 640) {
      const int which = tid >> 7, r = tid & 127;
      const unsigned* A = aggL + (which ? 8192 : 0);
      const uint2* x2p = (const uint2*)mPu[which];
      float acc = (which == 0) ? b_agg[r] : b_agg[D + r];
      #pragma unroll 8
      for (int e2g = 0; e2g < 32; ++e2g) {
        unsigned u0 = A[e2g*256 + r];
        unsigned u1 = A[e2g*256 + 128 + r];
        uint2 xu = x2p[e2g];
        acc = dot2(u0, xu.x, acc);
        acc = dot2(u1, xu.y, acc);
      }
      a_[which][r] = tanhf(acc);
    } else {
      const int r = tid - 640;
      const uint4* g2p4 = (const uint4*)g2Pu;
      float acc = b_query[r];
      #pragma unroll
      for (int k = 0; k < 16; ++k) {
        uint4 u = Wq4[k*128 + r];
        uint4 xu = g2p4[k];
        FD4(u, xu, acc);
      }
      kevec[r] = tanhf(acc) * w_k[r];
    }
    __syncthreads();

    // ---- P3: agg2 (0..255, per-wave redundant v) | og-prev (256..431) | kw-reduce (512..575) ----
    if (tid < 256) {
      const int l = tid & 63;
      float v0 = a_[0][2*l]   + 0.25f*(a_[1][2*l]  +a_[2][2*l]  +a_[3][2*l]  +a_[4][2*l]);
      float v1 = a_[0][2*l+1] + 0.25f*(a_[1][2*l+1]+a_[2][2*l+1]+a_[3][2*l+1]+a_[4][2*l+1]);
      vPu[l] = packh2(v0, v1);
      const int r = tid >> 1, h = tid & 1;
      const uint2* x2p = (const uint2*)vPu;
      float acc = h ? 0.f : b_agg[r];
      #pragma unroll
      for (int e2g = h*16; e2g < h*16+16; ++e2g) {
        unsigned u0 = aggL[e2g*256 + r];
        unsigned u1 = aggL[e2g*256 + 128 + r];
        uint2 xu = x2p[e2g];
        acc = dot2(u0, xu.x, acc);
        acc = dot2(u1, xu.y, acc);
      }
      acc += __shfl_xor(acc, 1);
      if (!h) ((_Float16*)m1Pu)[r] = (_Float16)tanhf(acc);
    } else if (tid >= 256 && tid < 432 && t >= 1) {
      const int g = (tid - 256) >> 4, lane = tid & 15;
      const int ne = (tp < RK ? tp : RK) + 1;
      if (g < ne) {
        const float* row;
        if (g == 0) row = g2fp[(t+1)&1];        // g2(t-1)
        else {
          int s = (tp <= RK) ? (g-1) : idxk[tp][g-1];
          row = hist[s];
          if (lane == 0) kwv[g] = kwh[s];
        }
        const float* qp = qcs[tp & 1];
        float part = 0.f;
        #pragma unroll
        for (int k = 0; k < 8; ++k) { int d = lane + (k<<4); part += qp[d]*row[d]; }
        part += __shfl_xor(part, 8, 16);
        part += __shfl_xor(part, 4, 16);
        part += __shfl_xor(part, 2, 16);
        part += __shfl_xor(part, 1, 16);
        if (lane == 0) ogv[g] = part;
      }
    } else if (tid >= 512 && tid < 576 && t >= 1) {
      const int lane = tid & 63;
      float v = kevec[lane] + kevec[lane + 64];
      #pragma unroll
      for (int off = 32; off; off >>= 1) v += __shfl_down(v, off);
      if (lane == 0) { kwv[0] = v; if (tp >= 1) kwh[tp] = v; }
    }
    __syncthreads();

    // ---- P4: ls -> xv packed (0..255) | y-write prev (tid 256) ----
    if (tid < 256) {
      const int r = tid >> 1, h = tid & 1;
      const unsigned* A = aggL + 16384;
      const uint2* x2p = (const uint2*)m1Pu;
      float acc = h ? 0.f : b_last[r];
      #pragma unroll
      for (int e2g = h*16; e2g < h*16+16; ++e2g) {
        unsigned u0 = A[e2g*256 + r];
        unsigned u1 = A[e2g*256 + 128 + r];
        uint2 xu = x2p[e2g];
        acc = dot2(u0, xu.x, acc);
        acc = dot2(u1, xu.y, acc);
      }
      acc += __shfl_xor(acc, 1);
      if (!h) ((_Float16*)xvPu)[r] = (_Float16)(smk[t] ? tanhf(acc) : e0[r]);
    } else if (tid == 256 && t >= 1) {
      const int ne = (tp < RK ? tp : RK) + 1;
      float mx = kwv[0];
      for (int i2 = 1; i2 < ne; ++i2) mx = fmaxf(mx, kwv[i2]);
      float den = 0.f, num = 0.f;
      for (int i2 = 0; i2 < ne; ++i2) { float e_ = expf(kwv[i2]-mx); den += e_; num += e_*ogv[i2]; }
      float val = num/den;
      y[b*SS + ((tp==0) ? 0 : (tp+1))] = 1.f/(1.f + expf(-val));
    }
    __syncthreads();

    // ---- P5: GRU1 matvecs (768, 2thr/row) ----
    {
      const uint4* xvp4 = (const uint4*)xvPu;
      const uint4* h1p4 = (const uint4*)h1Pu;
      float acc_i = hf ? 0.f : (b_ih1[r2] + gicorr[scc[t]][r2]);
      float acc_h = hf ? 0.f : b_hh1[r2];
      #pragma unroll
      for (int k = 0; k < 8; ++k) {
        uint4 u = Wi1[k*768 + tid];
        uint4 xu = xvp4[hf*8 + k];
        FD4(u, xu, acc_i);
      }
      #pragma unroll
      for (int k = 0; k < 8; ++k) {
        uint4 u = Wh1[k*768 + tid];
        uint4 xu = h1p4[hf*8 + k];
        FD4(u, xu, acc_h);
      }
      acc_i += __shfl_xor(acc_i, 1);
      acc_h += __shfl_xor(acc_h, 1);
      if (!hf) { gi1[r2] = acc_i; gh1[r2] = acc_h; }
    }
    __syncthreads();

    // ---- P6: per-wave redundant GRU1-nl (no barrier) + GRU2 matvecs (pinned) ----
    {
      const int l = tid & 63;
      float2 hold = ((const float2*)h1fp[(t+1)&1])[l];
      float2 hn = gru_nl2(((const float2*)gi1)[l], ((const float2*)(gi1+128))[l], ((const float2*)(gi1+256))[l],
                          ((const float2*)gh1)[l], ((const float2*)(gh1+128))[l], ((const float2*)(gh1+256))[l],
                          hold);
      ((float2*)h1fp[t&1])[l] = hn;
      h1Pu[l] = packh2(hn.x, hn.y);
    }
    {
      const uint4* xh1 = (const uint4*)h1Pu;
      const uint4* xh2 = (t <= 1) ? (const uint4*)h2iPu : (const uint4*)g2Pu;
      float acc_i = hf ? 0.f : b_ih2[r2];
      float acc_h = hf ? 0.f : b_hh2[r2];
      #pragma unroll
      for (int k = 0; k < 8; ++k) {
        uint4 xi = xh1[hf*8 + k];
        FD4(pwi[k], xi, acc_i);
        uint4 xx = xh2[hf*8 + k];
        FD4(pwh[k], xx, acc_h);
      }
      acc_i += __shfl_xor(acc_i, 1);
      acc_h += __shfl_xor(acc_h, 1);
      if (!hf) { gi2[r2] = acc_i; gh2[r2] = acc_h; }
    }
    __syncthreads();
  }

  // ==== epilogue: finalize g2(62), predict(62) -> y[63] ====
  if (tid < 64) {
    const int l = tid;
    const float* ph2 = g2fp[1];                 // g2(61)
    float2 hold = ((const float2*)ph2)[l];
    float2 gv = gru_nl2(((const float2*)gi2)[l], ((const float2*)(gi2+128))[l], ((const float2*)(gi2+256))[l],
                        ((const float2*)gh2)[l], ((const float2*)(gh2+128))[l], ((const float2*)(gh2+256))[l],
                        hold);
    ((float2*)g2fp[0])[l] = gv;
    g2Pu[l] = packh2(gv.x, gv.y);
  }
  __syncthreads();
  if (tid < 128) {
    const int r = tid;
    const uint4* g2p4 = (const uint4*)g2Pu;
    float acc = b_query[r];
    #pragma unroll
    for (int k = 0; k < 16; ++k) {
      uint4 u = Wq4[k*128 + r];
      uint4 xu = g2p4[k];
      FD4(u, xu, acc);
    }
    kevec[r] = tanhf(acc) * w_k[r];
  }
  __syncthreads();
  {
    const int tp = SS - 2;   // 62
    if (tid < 176) {
      const int g = tid >> 4, lane = tid & 15;
      const int ne = RK + 1;
      if (g < ne) {
        const float* row;
        if (g == 0) row = g2fp[0];
        else {
          int s = idxk[tp][g-1];
          row = hist[s];
          if (lane == 0) kwv[g] = kwh[s];
        }
        const float* qp = qcs[tp & 1];
        float part = 0.f;
        #pragma unroll
        for (int k = 0; k < 8; ++k) { int d = lane + (k<<4); part += qp[d]*row[d]; }
        part += __shfl_xor(part, 8, 16);
        part += __shfl_xor(part, 4, 16);
        part += __shfl_xor(part, 2, 16);
        part += __shfl_xor(part, 1, 16);
        if (lane == 0) ogv[g] = part;
      }
    } else if (tid >= 256 && tid < 320) {
      const int lane = tid & 63;
      float v = kevec[lane] + kevec[lane + 64];
      #pragma unroll
      for (int off = 32; off; off >>= 1) v += __shfl_down(v, off);
      if (lane == 0) kwv[0] = v;
    }
  }
  __syncthreads();
  if (tid == 0) {
    const int ne = RK + 1;
    float mx = kwv[0];
    for (int i2 = 1; i2 < ne; ++i2) mx = fmaxf(mx, kwv[i2]);
    float den = 0.f, num = 0.f;
    for (int i2 = 0; i2 < ne; ++i2) { float e_ = expf(kwv[i2]-mx); den += e_; num += e_*ogv[i2]; }
    float val = num/den;
    y[b*SS + SS - 1] = 1.f/(1.f + expf(-val));
  }
}

extern "C" void kernel_launch(void* const* d_in, const int* in_sizes, int n_in,
                              void* d_out, int out_size, void* d_ws, size_t ws_size,
                              hipStream_t stream)
{
  (void)in_sizes; (void)n_in; (void)out_size; (void)ws_size;

  const float* embQ  = (const float*)d_in[0];
  const float* embC  = (const float*)d_in[1];
  const float* embR  = (const float*)d_in[2];
  const float* Wih1  = (const float*)d_in[3];
  const float* Whh1  = (const float*)d_in[4];
  const float* bih1  = (const float*)d_in[5];
  const float* bhh1  = (const float*)d_in[6];
  const float* Wih2  = (const float*)d_in[7];
  const float* Whh2  = (const float*)d_in[8];
  const float* bih2  = (const float*)d_in[9];
  const float* bhh2  = (const float*)d_in[10];
  const float* Wagg  = (const float*)d_in[11];
  const float* bagg  = (const float*)d_in[12];
  const float* Wlast = (const float*)d_in[13];
  const float* blast = (const float*)d_in[14];
  const float* Wqry  = (const float*)d_in[15];
  const float* bqry  = (const float*)d_in[16];
  // d_in[17] W_key, [18] b_key, [19] w_q, [21] b_w cancel in the softmax -> unused
  const float* wk    = (const float*)d_in[20];
  const float* h1i   = (const float*)d_in[22];
  const float* h2i   = (const float*)d_in[23];
  const int* qnbr    = (const int*)d_in[24];
  const int* cnbr    = (const int*)d_in[25];
  const int* q2c     = (const int*)d_in[26];
  const int* qseq    = (const int*)d_in[27];
  const int* cseq    = (const int*)d_in[28];
  const int* mseq    = (const int*)d_in[29];

  unsigned* wsU = (unsigned*)d_ws;
  float* yout = (float*)d_out;

  gikt_pack<<<(TOTAL_U + 255) / 256, 256, 0, stream>>>(Wih1, Whh1, Wih2, Whh2, Wagg, Wlast, Wqry, wsU);
  gikt_main<<<BB, T, 0, stream>>>(embQ, embC, embR, bih1, bhh1, bih2, bhh2, bagg, blast, bqry,
                                  wk, h1i, h2i, qnbr, cnbr, q2c, qseq, cseq, mseq, wsU, yout);
}

// Round 6
// 640.354 us; speedup vs baseline: 2.7605x; 1.2102x over previous
//
#include <hip/hip_runtime.h>
#include <math.h>

#define D    128
#define QN   4
#define CN   4
#define MAXC 4
#define BB   128
#define SS   64
#define RK   10
#define T    768   // 12 waves

// ---- packed-fp16 weight workspace layout (uint32 units; each uint = 2 half) ----
#define UOFF_IH1A 0        // cols 0..127 of W_ih1, chunked NT=768 K=8 (pinned) -> 24576
#define UOFF_IH1B 24576    // cols 128..255 of W_ih1: [e2l][384] -> 24576
#define UOFF_HH1  49152    // chunked NT=768 K=8 (pinned) -> 24576
#define UOFF_IH2  73728    // chunked NT=768 K=8 (pinned) -> 24576
#define UOFF_HH2  98304    // chunked NT=768 K=8 (pinned) -> 24576
#define UOFF_QRY  122880   // [k][128] uint4, K=16 -> 8192
#define UOFF_A0   131072   // [e2g][2][128] -> 8192
#define UOFF_A1   139264   // -> 8192
#define UOFF_LS   147456   // -> 8192
#define TOTAL_U   155648

typedef _Float16 h2_t __attribute__((ext_vector_type(2)));
union U32H2 { unsigned u; h2_t h; unsigned short s2[2]; };

__device__ __forceinline__ unsigned h16f(float x){
  U32H2 c; c.h[0] = (_Float16)x; c.h[1] = (_Float16)0.f;
  return (unsigned)c.s2[0];
}
__device__ __forceinline__ unsigned packh2(float a, float b){
  U32H2 c; c.h[0] = (_Float16)a; c.h[1] = (_Float16)b;
  return c.u;
}
__device__ __forceinline__ float dot2(unsigned w, unsigned x, float acc){
  U32H2 a; a.u = w; U32H2 b; b.u = x;
  return __builtin_amdgcn_fdot2(a.h, b.h, acc, false);
}
__device__ __forceinline__ float hlo(unsigned u){ U32H2 a; a.u=u; return (float)a.h[0]; }
__device__ __forceinline__ float hhi(unsigned u){ U32H2 a; a.u=u; return (float)a.h[1]; }

__device__ __forceinline__ float fsig(float x){ return 1.f/(1.f + __expf(-x)); }
__device__ __forceinline__ float ftanh(float x){
  float xc = fminf(fmaxf(x, -30.f), 30.f);
  float e = __expf(2.f*xc);
  return (e - 1.f)/(e + 1.f);
}

#define FD4(w4, x4, acc) { \
  acc = dot2((w4).x, (x4).x, acc); acc = dot2((w4).y, (x4).y, acc); \
  acc = dot2((w4).z, (x4).z, acc); acc = dot2((w4).w, (x4).w, acc); }

__global__ void gikt_pack(const float* __restrict__ Wih1,
                          const float* __restrict__ Whh1,
                          const float* __restrict__ Wih2,
                          const float* __restrict__ Whh2,
                          const float* __restrict__ Wagg,
                          const float* __restrict__ Wlast,
                          const float* __restrict__ Wqry,
                          unsigned* __restrict__ wsU)
{
  int i = blockIdx.x * blockDim.x + threadIdx.x;
  if (i >= TOTAL_U) return;
  const float* src = nullptr; int row = 0, e2 = 0, stride = 0;
  int j = i;
  if (j < 24576) {               // ih1a
    int c = j & 3, i4 = j >> 2, k = i4 / 768, t = i4 - k * 768, r = t >> 1, hf = t & 1;
    e2 = hf * 32 + k * 4 + c; row = r; src = Wih1; stride = 256;
  } else if ((j -= 24576) < 24576) {   // ih1b
    e2 = 64 + (j / 384); row = j % 384; src = Wih1; stride = 256;
  } else if ((j -= 24576) < 24576) {   // hh1
    int c = j & 3, i4 = j >> 2, k = i4 / 768, t = i4 - k * 768, r = t >> 1, hf = t & 1;
    e2 = hf * 32 + k * 4 + c; row = r; src = Whh1; stride = 128;
  } else if ((j -= 24576) < 24576) {   // ih2
    int c = j & 3, i4 = j >> 2, k = i4 / 768, t = i4 - k * 768, r = t >> 1, hf = t & 1;
    e2 = hf * 32 + k * 4 + c; row = r; src = Wih2; stride = 128;
  } else if ((j -= 24576) < 24576) {   // hh2
    int c = j & 3, i4 = j >> 2, k = i4 / 768, t = i4 - k * 768, r = t >> 1, hf = t & 1;
    e2 = hf * 32 + k * 4 + c; row = r; src = Whh2; stride = 128;
  } else if ((j -= 24576) < 8192) {    // qry
    int c = j & 3, i4 = j >> 2, k = i4 >> 7, r = i4 & 127;
    e2 = k * 4 + c; row = r; src = Wqry; stride = 128;
  } else if ((j -= 8192) < 8192) {     // a0
    int r = j & 127, p = (j >> 7) & 1, e2g = j >> 8;
    e2 = 2 * e2g + p; row = r; src = Wagg; stride = 128;
  } else if ((j -= 8192) < 8192) {     // a1
    int r = j & 127, p = (j >> 7) & 1, e2g = j >> 8;
    e2 = 2 * e2g + p; row = r; src = Wagg + 128 * 128; stride = 128;
  } else {                              // ls
    j -= 8192;
    int r = j & 127, p = (j >> 7) & 1, e2g = j >> 8;
    e2 = 2 * e2g + p; row = r; src = Wlast; stride = 128;
  }
  float lo = src[row * stride + 2 * e2];
  float hi = src[row * stride + 2 * e2 + 1];
  wsU[i] = h16f(lo) | (h16f(hi) << 16);
}

__device__ __forceinline__ float2 gru_nl2(float2 gr, float2 gz, float2 gn,
                                          float2 hr, float2 hz, float2 hn,
                                          float2 hold){
  float2 out;
  {
    float rg = fsig(gr.x + hr.x);
    float zg = fsig(gz.x + hz.x);
    float ng = ftanh(gn.x + rg*hn.x);
    out.x = (1.f-zg)*ng + zg*hold.x;
  }
  {
    float rg = fsig(gr.y + hr.y);
    float zg = fsig(gz.y + hz.y);
    float ng = ftanh(gn.y + rg*hn.y);
    out.y = (1.f-zg)*ng + zg*hold.y;
  }
  return out;
}

__launch_bounds__(T, 1)
__global__ void gikt_main(
    const float* __restrict__ embQ,
    const float* __restrict__ embC,
    const float* __restrict__ embR,
    const float* __restrict__ b_ih1,
    const float* __restrict__ b_hh1,
    const float* __restrict__ b_ih2,
    const float* __restrict__ b_hh2,
    const float* __restrict__ b_agg,
    const float* __restrict__ b_last,
    const float* __restrict__ b_query,
    const float* __restrict__ w_k,
    const float* __restrict__ h1i,
    const float* __restrict__ h2i,
    const int* __restrict__ qnbr,
    const int* __restrict__ cnbr,
    const int* __restrict__ q2c,
    const int* __restrict__ qseq,
    const int* __restrict__ cseq,
    const int* __restrict__ mseq,
    const unsigned* __restrict__ wsU,
    float* __restrict__ y)
{
  const int b   = blockIdx.x;
  const int tid = threadIdx.x;
  const int r2  = tid >> 1, hf = tid & 1;

  __shared__ unsigned aggL[3 * 8192];          // a0|a1|ls; phase0 alias: Gram
  __shared__ __align__(16) float hist[SS][132];// state history fp32 (row0 = zero)
  __shared__ float gicorr[2][384];
  __shared__ int   idxk[SS][RK];
  __shared__ float kwh[SS];
  __shared__ __align__(16) float a_[5][D];
  __shared__ __align__(16) float gi1[3*D];
  __shared__ __align__(16) float gh1[3*D];
  __shared__ __align__(16) float gi2[3*D];
  __shared__ __align__(16) float gh2[3*D];
  __shared__ __align__(16) float h1fp[2][D];
  __shared__ __align__(16) float g2fp[2][D];
  __shared__ __align__(16) float h2ifp[D];
  __shared__ float e0[D];
  __shared__ __align__(16) float qcs[2][D];
  __shared__ float kevec[D];
  __shared__ __align__(16) unsigned mPu[5][64];
  __shared__ __align__(16) unsigned vPu[64];
  __shared__ __align__(16) unsigned m1Pu[64];
  __shared__ __align__(16) unsigned xvPu[64];
  __shared__ __align__(16) unsigned h1Pu[64];
  __shared__ __align__(16) unsigned g2Pu[64];
  __shared__ __align__(16) unsigned h2iPu[64];
  __shared__ int   sq[SS], scc[SS], smk[SS];
  __shared__ int   nn1[SS][QN], nn2[SS][QN*CN], cc2[SS][MAXC];
  __shared__ float red[12];
  __shared__ float ogv[16], kwv[16];

  float (*G)[65] = (float(*)[65])aggL;

  // ---- pinned weights: GRU1 (ih1a + hh1) and GRU2 (ih2 + hh2): 32 uint4 = 128 VGPR ----
  uint4 pw1i[8], pw1h[8], pwi[8], pwh[8];
  {
    const uint4* Pa = (const uint4*)(wsU + UOFF_IH1A);
    const uint4* Pb = (const uint4*)(wsU + UOFF_HH1);
    const uint4* Pi = (const uint4*)(wsU + UOFF_IH2);
    const uint4* Ph = (const uint4*)(wsU + UOFF_HH2);
    #pragma unroll
    for (int k = 0; k < 8; ++k) {
      pw1i[k] = Pa[k*768 + tid]; pw1h[k] = Pb[k*768 + tid];
      pwi[k]  = Pi[k*768 + tid]; pwh[k]  = Ph[k*768 + tid];
    }
  }

  // ---- phase 0a: sequences ----
  for (int i = tid; i < SS; i += T) { sq[i]=qseq[b*SS+i]; scc[i]=cseq[b*SS+i]; smk[i]=mseq[b*SS+i]; }
  __syncthreads();

  // ---- phase 0b: E rows into hist; 1-hop indices ----
  for (int i = tid; i < SS*32; i += T) {
    int s = i >> 5, e4 = i & 31;
    float4 v = ((const float4*)(embQ + sq[s]*D))[e4];
    ((float4*)hist[s])[e4] = v;
  }
  for (int i = tid; i < (SS-1)*QN; i += T)   { int t = i>>2, j = i&3; nn1[t][j] = qnbr[sq[t]*QN + j]; }
  for (int i = tid; i < (SS-1)*MAXC; i += T) { int t = i>>2, j = i&3; cc2[t][j] = q2c[sq[t+1]*MAXC + j]; }
  __syncthreads();

  // ---- phase 0c: Gram (fp32, float4), 2-hop indices, gicorr ----
  for (int p = tid; p < SS*SS; p += T) {
    int tq = p >> 6, s = p & 63;
    if (tq >= RK+2 && s < tq-1) {
      const float4* ra = (const float4*)hist[tq];
      const float4* rb = (const float4*)hist[s];
      float acc = 0.f;
      #pragma unroll 8
      for (int d4 = 0; d4 < 32; ++d4) {
        float4 xa = ra[d4], xb = rb[d4];
        acc += xa.x*xb.x + xa.y*xb.y + xa.z*xb.z + xa.w*xb.w;
      }
      G[tq-(RK+2)][s] = acc;
    }
  }
  for (int i = tid; i < (SS-1)*QN*CN; i += T) {
    int t = i>>4, j = (i>>2)&3, l = i&3;
    nn2[t][j*CN+l] = cnbr[nn1[t][j]*CN + l];
  }
  {
    const int c = (tid >= 384) ? 1 : 0, r = tid - (c ? 384 : 0);
    const float2* er2 = (const float2*)(embR + c*D);
    float acc = 0.f;
    #pragma unroll 4
    for (int e2l = 0; e2l < 64; ++e2l) {
      unsigned u = wsU[UOFF_IH1B + e2l*384 + r];
      float2 x = er2[e2l];
      acc += hlo(u)*x.x + hhi(u)*x.y;
    }
    gicorr[c][r] = acc;
  }
  __syncthreads();

  // ---- phase 0d: stable top-k (ties -> lowest index, = jax.lax.top_k) ----
  if (tid < 52) {
    int t = RK + 1 + tid;
    for (int k = 0; k < RK; ++k) {
      float best = -INFINITY; int bi = 0;
      for (int s = 0; s < t; ++s) { float v = G[tid][s]; if (v > best) { best = v; bi = s; } }
      idxk[t][k] = bi;
      G[tid][bi] = -INFINITY;
    }
  }
  __syncthreads();

  // ---- phase 0e: agg weights into LDS; state init; kw(zero-state) ----
  for (int i = tid; i < 3*8192; i += T) aggL[i] = wsU[UOFF_A0 + i];
  if (tid < 64) {
    float a0 = h1i[b*D+2*tid], a1 = h1i[b*D+2*tid+1];
    h1Pu[tid] = packh2(a0, a1);
    ((float2*)h1fp[1])[tid] = make_float2(a0, a1);
    float c0 = h2i[b*D+2*tid], c1 = h2i[b*D+2*tid+1];
    h2iPu[tid] = packh2(c0, c1);
    ((float2*)h2ifp)[tid] = make_float2(c0, c1);
    g2Pu[tid] = 0;
  }
  if (tid < D) hist[0][tid] = 0.f;
  if (tid == 0) y[b*SS + 1] = 0.f;   // never written by reference
  {
    float p0 = (tid < D) ? w_k[tid]*ftanh(b_query[tid]) : 0.f;
    #pragma unroll
    for (int off = 32; off; off >>= 1) p0 += __shfl_down(p0, off);
    if ((tid & 63) == 0) red[tid >> 6] = p0;
  }
  __syncthreads();
  if (tid == 0) kwh[0] = red[0]+red[1];
  __syncthreads();

  const uint4* Wq4 = (const uint4*)(wsU + UOFF_QRY);

  // ==== time loop: step t runs GRU(t); g2(t-1) finalizes in P1; predict(t-1) overlapped ====
  for (int t = 0; t < SS-1; ++t) {
    const int tp = t - 1;
    const bool msk = (smk[t] != 0);

    // ---- P1: wave0 finalizes g2(t-1); gather (full if mask, lite if not) ----
    if (tid < 64 && t >= 1) {
      const int l = tid;
      const float* ph2 = (t <= 2) ? h2ifp : g2fp[t & 1];
      float2 hold = ((const float2*)ph2)[l];
      float2 gv = gru_nl2(((const float2*)gi2)[l], ((const float2*)(gi2+128))[l], ((const float2*)(gi2+256))[l],
                          ((const float2*)gh2)[l], ((const float2*)(gh2+128))[l], ((const float2*)(gh2+256))[l],
                          hold);
      ((float2*)g2fp[(t+1)&1])[l] = gv;
      g2Pu[l] = packh2(gv.x, gv.y);
      if (t >= 2) { hist[t-1][2*l] = gv.x; hist[t-1][2*l+1] = gv.y; }
    }
    if (msk) {
      const int d   = tid & 127;
      const int grp = tid >> 7;
      if (grp == 0) {
        float ev = embQ[sq[t]*D + d];
        float s1 = embC[nn1[t][0]*D+d]+embC[nn1[t][1]*D+d]+embC[nn1[t][2]*D+d]+embC[nn1[t][3]*D+d];
        ((_Float16*)mPu[0])[d] = (_Float16)(ev + 0.25f*s1);
      } else if (grp <= 4) {
        const int j = grp - 1;
        float e1v = embC[nn1[t][j]*D + d];
        float s2  = embQ[nn2[t][j*CN+0]*D+d]+embQ[nn2[t][j*CN+1]*D+d]
                   +embQ[nn2[t][j*CN+2]*D+d]+embQ[nn2[t][j*CN+3]*D+d];
        ((_Float16*)mPu[grp])[d] = (_Float16)(e1v + 0.25f*s2);
      } else {
        float acc = embQ[sq[t+1]*D + d];
        #pragma unroll
        for (int mm = 0; mm < MAXC; ++mm) acc += embC[cc2[t][mm]*D + d];
        qcs[t & 1][d] = acc;
      }
    } else {
      const int d   = tid & 127;
      const int grp = tid >> 7;
      if (grp == 0) {
        ((_Float16*)xvPu)[d] = (_Float16)(embQ[sq[t]*D + d]);   // xv = e0 directly
      } else if (grp == 5) {
        float acc = embQ[sq[t+1]*D + d];
        #pragma unroll
        for (int mm = 0; mm < MAXC; ++mm) acc += embC[cc2[t][mm]*D + d];
        qcs[t & 1][d] = acc;
      }
    }
    __syncthreads();

    if (msk) {
      // ---- P2: agg1 (0..255) | og-prev (256..431) | qry (512..767, 2thr/row) ----
      if (tid < 128) {             // a0 = tanh(A0 @ m0 + b)
        const int r = tid;
        const unsigned* A = aggL;
        const uint2* x2p = (const uint2*)mPu[0];
        float acc0 = b_agg[r], acc1 = 0.f;
        #pragma unroll
        for (int e2g = 0; e2g < 32; e2g += 2) {
          unsigned u00 = A[e2g*256 + r],     u01 = A[e2g*256 + 128 + r];
          uint2 x0 = x2p[e2g];
          acc0 = dot2(u00, x0.x, acc0); acc0 = dot2(u01, x0.y, acc0);
          unsigned u10 = A[(e2g+1)*256 + r], u11 = A[(e2g+1)*256 + 128 + r];
          uint2 x1 = x2p[e2g+1];
          acc1 = dot2(u10, x1.x, acc1); acc1 = dot2(u11, x1.y, acc1);
        }
        a_[0][r] = ftanh(acc0 + acc1);
      } else if (tid < 256) {      // a1..a4 share the A1 row read (4 acc chains)
        const int r = tid - 128;
        const unsigned* A = aggL + 8192;
        const uint2* x1p = (const uint2*)mPu[1];
        const uint2* x2p = (const uint2*)mPu[2];
        const uint2* x3p = (const uint2*)mPu[3];
        const uint2* x4p = (const uint2*)mPu[4];
        float bb = b_agg[D + r];
        float c1 = 0.f, c2 = 0.f, c3 = 0.f, c4 = 0.f;
        #pragma unroll
        for (int e2g = 0; e2g < 32; ++e2g) {
          unsigned u0 = A[e2g*256 + r], u1 = A[e2g*256 + 128 + r];
          uint2 v1 = x1p[e2g]; c1 = dot2(u0, v1.x, c1); c1 = dot2(u1, v1.y, c1);
          uint2 v2 = x2p[e2g]; c2 = dot2(u0, v2.x, c2); c2 = dot2(u1, v2.y, c2);
          uint2 v3 = x3p[e2g]; c3 = dot2(u0, v3.x, c3); c3 = dot2(u1, v3.y, c3);
          uint2 v4 = x4p[e2g]; c4 = dot2(u0, v4.x, c4); c4 = dot2(u1, v4.y, c4);
        }
        a_[1][r] = ftanh(bb + c1); a_[2][r] = ftanh(bb + c2);
        a_[3][r] = ftanh(bb + c3); a_[4][r] = ftanh(bb + c4);
      } else if (tid < 432 && t >= 1) {   // og dots for predict(t-1)
        const int g = (tid - 256) >> 4, lane = tid & 15;
        const int ne = (tp < RK ? tp : RK) + 1;
        if (g < ne) {
          const float* row;
          if (g == 0) row = g2fp[(t+1)&1];
          else {
            int s = (tp <= RK) ? (g-1) : idxk[tp][g-1];
            row = hist[s];
            if (lane == 0) kwv[g] = kwh[s];
          }
          const float* qp = qcs[tp & 1];
          float part = 0.f;
          #pragma unroll
          for (int k = 0; k < 8; ++k) { int d = lane + (k<<4); part += qp[d]*row[d]; }
          part += __shfl_xor(part, 8, 16);
          part += __shfl_xor(part, 4, 16);
          part += __shfl_xor(part, 2, 16);
          part += __shfl_xor(part, 1, 16);
          if (lane == 0) ogv[g] = part;
        }
      } else if (tid >= 512) {     // qry on g2(t-1), 2 thr/row
        const int rq = (tid - 512) >> 1, hq = tid & 1;
        const uint4* g2p4 = (const uint4*)g2Pu;
        float a0 = hq ? 0.f : b_query[rq], a1 = 0.f;
        #pragma unroll
        for (int k = hq*8; k < hq*8+8; k += 2) {
          uint4 u0 = Wq4[k*128 + rq];     uint4 x0 = g2p4[k];   FD4(u0, x0, a0);
          uint4 u1 = Wq4[(k+1)*128 + rq]; uint4 x1 = g2p4[k+1]; FD4(u1, x1, a1);
        }
        float acc = a0 + a1; acc += __shfl_xor(acc, 1);
        if (!hq) kevec[rq] = ftanh(acc) * w_k[rq];
      }
      __syncthreads();

      // ---- P3: agg2 (0..255) | kw-reduce (512..575) ----
      if (tid < 256) {
        const int l = tid & 63;
        float v0 = a_[0][2*l]   + 0.25f*(a_[1][2*l]  +a_[2][2*l]  +a_[3][2*l]  +a_[4][2*l]);
        float v1 = a_[0][2*l+1] + 0.25f*(a_[1][2*l+1]+a_[2][2*l+1]+a_[3][2*l+1]+a_[4][2*l+1]);
        vPu[l] = packh2(v0, v1);
        const int r = tid >> 1, h = tid & 1;
        const uint2* x2p = (const uint2*)vPu;
        float acc0 = h ? 0.f : b_agg[r], acc1 = 0.f;
        #pragma unroll
        for (int e2g = h*16; e2g < h*16+16; e2g += 2) {
          unsigned u00 = aggL[e2g*256 + r],     u01 = aggL[e2g*256 + 128 + r];
          uint2 x0 = x2p[e2g];
          acc0 = dot2(u00, x0.x, acc0); acc0 = dot2(u01, x0.y, acc0);
          unsigned u10 = aggL[(e2g+1)*256 + r], u11 = aggL[(e2g+1)*256 + 128 + r];
          uint2 x1 = x2p[e2g+1];
          acc1 = dot2(u10, x1.x, acc1); acc1 = dot2(u11, x1.y, acc1);
        }
        float acc = acc0 + acc1; acc += __shfl_xor(acc, 1);
        if (!h) ((_Float16*)m1Pu)[r] = (_Float16)ftanh(acc);
      } else if (tid >= 512 && tid < 576 && t >= 1) {
        const int lane = tid & 63;
        float v = kevec[lane] + kevec[lane + 64];
        #pragma unroll
        for (int off = 32; off; off >>= 1) v += __shfl_down(v, off);
        if (lane == 0) { kwv[0] = v; if (tp >= 1) kwh[tp] = v; }
      }
      __syncthreads();

      // ---- P4: ls -> xvPu (0..255) | y-write prev (tid 256) ----
      if (tid < 256) {
        const int r = tid >> 1, h = tid & 1;
        const unsigned* A = aggL + 16384;
        const uint2* x2p = (const uint2*)m1Pu;
        float acc0 = h ? 0.f : b_last[r], acc1 = 0.f;
        #pragma unroll
        for (int e2g = h*16; e2g < h*16+16; e2g += 2) {
          unsigned u00 = A[e2g*256 + r],     u01 = A[e2g*256 + 128 + r];
          uint2 x0 = x2p[e2g];
          acc0 = dot2(u00, x0.x, acc0); acc0 = dot2(u01, x0.y, acc0);
          unsigned u10 = A[(e2g+1)*256 + r], u11 = A[(e2g+1)*256 + 128 + r];
          uint2 x1 = x2p[e2g+1];
          acc1 = dot2(u10, x1.x, acc1); acc1 = dot2(u11, x1.y, acc1);
        }
        float acc = acc0 + acc1; acc += __shfl_xor(acc, 1);
        if (!h) ((_Float16*)xvPu)[r] = (_Float16)ftanh(acc);
      } else if (tid == 256 && t >= 1) {
        const int ne = (tp < RK ? tp : RK) + 1;
        float mx = kwv[0];
        for (int i2 = 1; i2 < ne; ++i2) mx = fmaxf(mx, kwv[i2]);
        float den = 0.f, num = 0.f;
        for (int i2 = 0; i2 < ne; ++i2) { float e_ = __expf(kwv[i2]-mx); den += e_; num += e_*ogv[i2]; }
        y[b*SS + ((tp==0) ? 0 : (tp+1))] = fsig(num/den);
      }
      __syncthreads();

      // ---- P5: GRU1 (pinned weights, pure LDS broadcast) ----
      {
        const uint4* xvp4 = (const uint4*)xvPu;
        const uint4* h1p4 = (const uint4*)h1Pu;
        float ai0 = hf ? 0.f : (b_ih1[r2] + gicorr[scc[t]][r2]), ai1 = 0.f;
        float ah0 = hf ? 0.f : b_hh1[r2], ah1 = 0.f;
        #pragma unroll
        for (int k = 0; k < 8; k += 2) {
          uint4 xa = xvp4[hf*8+k], xb = xvp4[hf*8+k+1];
          FD4(pw1i[k], xa, ai0); FD4(pw1i[k+1], xb, ai1);
          uint4 ya = h1p4[hf*8+k], yb = h1p4[hf*8+k+1];
          FD4(pw1h[k], ya, ah0); FD4(pw1h[k+1], yb, ah1);
        }
        float acc_i = ai0 + ai1; acc_i += __shfl_xor(acc_i, 1);
        float acc_h = ah0 + ah1; acc_h += __shfl_xor(acc_h, 1);
        if (!hf) { gi1[r2] = acc_i; gh1[r2] = acc_h; }
      }
      __syncthreads();
    } else {
      // ---- P2'' (mask==0): og + qry pre-work, then GRU1 on all threads ----
      if (tid >= 256 && tid < 432 && t >= 1) {
        const int g = (tid - 256) >> 4, lane = tid & 15;
        const int ne = (tp < RK ? tp : RK) + 1;
        if (g < ne) {
          const float* row;
          if (g == 0) row = g2fp[(t+1)&1];
          else {
            int s = (tp <= RK) ? (g-1) : idxk[tp][g-1];
            row = hist[s];
            if (lane == 0) kwv[g] = kwh[s];
          }
          const float* qp = qcs[tp & 1];
          float part = 0.f;
          #pragma unroll
          for (int k = 0; k < 8; ++k) { int d = lane + (k<<4); part += qp[d]*row[d]; }
          part += __shfl_xor(part, 8, 16);
          part += __shfl_xor(part, 4, 16);
          part += __shfl_xor(part, 2, 16);
          part += __shfl_xor(part, 1, 16);
          if (lane == 0) ogv[g] = part;
        }
      } else if (tid >= 512) {
        const int rq = (tid - 512) >> 1, hq = tid & 1;
        const uint4* g2p4 = (const uint4*)g2Pu;
        float a0 = hq ? 0.f : b_query[rq], a1 = 0.f;
        #pragma unroll
        for (int k = hq*8; k < hq*8+8; k += 2) {
          uint4 u0 = Wq4[k*128 + rq];     uint4 x0 = g2p4[k];   FD4(u0, x0, a0);
          uint4 u1 = Wq4[(k+1)*128 + rq]; uint4 x1 = g2p4[k+1]; FD4(u1, x1, a1);
        }
        float acc = a0 + a1; acc += __shfl_xor(acc, 1);
        if (!hq) kevec[rq] = ftanh(acc) * w_k[rq];
      }
      {
        const uint4* xvp4 = (const uint4*)xvPu;
        const uint4* h1p4 = (const uint4*)h1Pu;
        float ai0 = hf ? 0.f : (b_ih1[r2] + gicorr[scc[t]][r2]), ai1 = 0.f;
        float ah0 = hf ? 0.f : b_hh1[r2], ah1 = 0.f;
        #pragma unroll
        for (int k = 0; k < 8; k += 2) {
          uint4 xa = xvp4[hf*8+k], xb = xvp4[hf*8+k+1];
          FD4(pw1i[k], xa, ai0); FD4(pw1i[k+1], xb, ai1);
          uint4 ya = h1p4[hf*8+k], yb = h1p4[hf*8+k+1];
          FD4(pw1h[k], ya, ah0); FD4(pw1h[k+1], yb, ah1);
        }
        float acc_i = ai0 + ai1; acc_i += __shfl_xor(acc_i, 1);
        float acc_h = ah0 + ah1; acc_h += __shfl_xor(acc_h, 1);
        if (!hf) { gi1[r2] = acc_i; gh1[r2] = acc_h; }
      }
      __syncthreads();
    }

    // ---- P6: [mask==0: wave0 kw+y] ; redundant GRU1-nl ; GRU2 (pinned) ----
    if (!msk && t >= 1 && tid < 64) {
      float v = kevec[tid] + kevec[tid + 64];
      #pragma unroll
      for (int off = 32; off; off >>= 1) v += __shfl_down(v, off);
      if (tid == 0) {
        if (tp >= 1) kwh[tp] = v;
        const int ne = (tp < RK ? tp : RK) + 1;
        float mx = v;
        for (int i2 = 1; i2 < ne; ++i2) mx = fmaxf(mx, kwv[i2]);
        float den = __expf(v - mx), num = den*ogv[0];
        for (int i2 = 1; i2 < ne; ++i2) { float e_ = __expf(kwv[i2]-mx); den += e_; num += e_*ogv[i2]; }
        y[b*SS + ((tp==0) ? 0 : (tp+1))] = fsig(num/den);
      }
    }
    {
      const int l = tid & 63;
      float2 hold = ((const float2*)h1fp[(t+1)&1])[l];
      float2 hn = gru_nl2(((const float2*)gi1)[l], ((const float2*)(gi1+128))[l], ((const float2*)(gi1+256))[l],
                          ((const float2*)gh1)[l], ((const float2*)(gh1+128))[l], ((const float2*)(gh1+256))[l],
                          hold);
      ((float2*)h1fp[t&1])[l] = hn;
      h1Pu[l] = packh2(hn.x, hn.y);
    }
    {
      const uint4* xh1 = (const uint4*)h1Pu;
      const uint4* xh2 = (t <= 1) ? (const uint4*)h2iPu : (const uint4*)g2Pu;
      float ai0 = hf ? 0.f : b_ih2[r2], ai1 = 0.f;
      float ah0 = hf ? 0.f : b_hh2[r2], ah1 = 0.f;
      #pragma unroll
      for (int k = 0; k < 8; k += 2) {
        uint4 xa = xh1[hf*8+k], xb = xh1[hf*8+k+1];
        FD4(pwi[k], xa, ai0); FD4(pwi[k+1], xb, ai1);
        uint4 ya = xh2[hf*8+k], yb = xh2[hf*8+k+1];
        FD4(pwh[k], ya, ah0); FD4(pwh[k+1], yb, ah1);
      }
      float acc_i = ai0 + ai1; acc_i += __shfl_xor(acc_i, 1);
      float acc_h = ah0 + ah1; acc_h += __shfl_xor(acc_h, 1);
      if (!hf) { gi2[r2] = acc_i; gh2[r2] = acc_h; }
    }
    __syncthreads();
  }

  // ==== epilogue: finalize g2(62), predict(62) -> y[63] ====
  if (tid < 64) {
    const int l = tid;
    const float* ph2 = g2fp[1];
    float2 hold = ((const float2*)ph2)[l];
    float2 gv = gru_nl2(((const float2*)gi2)[l], ((const float2*)(gi2+128))[l], ((const float2*)(gi2+256))[l],
                        ((const float2*)gh2)[l], ((const float2*)(gh2+128))[l], ((const float2*)(gh2+256))[l],
                        hold);
    ((float2*)g2fp[0])[l] = gv;
    g2Pu[l] = packh2(gv.x, gv.y);
  }
  __syncthreads();
  if (tid < 128) {
    const int r = tid;
    const uint4* g2p4 = (const uint4*)g2Pu;
    float a0 = b_query[r], a1 = 0.f;
    #pragma unroll
    for (int k = 0; k < 16; k += 2) {
      uint4 u0 = Wq4[k*128 + r];     uint4 x0 = g2p4[k];   FD4(u0, x0, a0);
      uint4 u1 = Wq4[(k+1)*128 + r]; uint4 x1 = g2p4[k+1]; FD4(u1, x1, a1);
    }
    kevec[r] = ftanh(a0 + a1) * w_k[r];
  }
  __syncthreads();
  {
    const int tp = SS - 2;   // 62
    if (tid < 176) {
      const int g = tid >> 4, lane = tid & 15;
      const int ne = RK + 1;
      if (g < ne) {
        const float* row;
        if (g == 0) row = g2fp[0];
        else {
          int s = idxk[tp][g-1];
          row = hist[s];
          if (lane == 0) kwv[g] = kwh[s];
        }
        const float* qp = qcs[tp & 1];
        float part = 0.f;
        #pragma unroll
        for (int k = 0; k < 8; ++k) { int d = lane + (k<<4); part += qp[d]*row[d]; }
        part += __shfl_xor(part, 8, 16);
        part += __shfl_xor(part, 4, 16);
        part += __shfl_xor(part, 2, 16);
        part += __shfl_xor(part, 1, 16);
        if (lane == 0) ogv[g] = part;
      }
    } else if (tid >= 256 && tid < 320) {
      const int lane = tid & 63;
      float v = kevec[lane] + kevec[lane + 64];
      #pragma unroll
      for (int off = 32; off; off >>= 1) v += __shfl_down(v, off);
      if (lane == 0) kwv[0] = v;
    }
  }
  __syncthreads();
  if (tid == 0) {
    const int ne = RK + 1;
    float mx = kwv[0];
    for (int i2 = 1; i2 < ne; ++i2) mx = fmaxf(mx, kwv[i2]);
    float den = 0.f, num = 0.f;
    for (int i2 = 0; i2 < ne; ++i2) { float e_ = __expf(kwv[i2]-mx); den += e_; num += e_*ogv[i2]; }
    y[b*SS + SS - 1] = fsig(num/den);
  }
}

extern "C" void kernel_launch(void* const* d_in, const int* in_sizes, int n_in,
                              void* d_out, int out_size, void* d_ws, size_t ws_size,
                              hipStream_t stream)
{
  (void)in_sizes; (void)n_in; (void)out_size; (void)ws_size;

  const float* embQ  = (const float*)d_in[0];
  const float* embC  = (const float*)d_in[1];
  const float* embR  = (const float*)d_in[2];
  const float* Wih1  = (const float*)d_in[3];
  const float* Whh1  = (const float*)d_in[4];
  const float* bih1  = (const float*)d_in[5];
  const float* bhh1  = (const float*)d_in[6];
  const float* Wih2  = (const float*)d_in[7];
  const float* Whh2  = (const float*)d_in[8];
  const float* bih2  = (const float*)d_in[9];
  const float* bhh2  = (const float*)d_in[10];
  const float* Wagg  = (const float*)d_in[11];
  const float* bagg  = (const float*)d_in[12];
  const float* Wlast = (const float*)d_in[13];
  const float* blast = (const float*)d_in[14];
  const float* Wqry  = (const float*)d_in[15];
  const float* bqry  = (const float*)d_in[16];
  // d_in[17] W_key, [18] b_key, [19] w_q, [21] b_w cancel in the softmax -> unused
  const float* wk    = (const float*)d_in[20];
  const float* h1i   = (const float*)d_in[22];
  const float* h2i   = (const float*)d_in[23];
  const int* qnbr    = (const int*)d_in[24];
  const int* cnbr    = (const int*)d_in[25];
  const int* q2c     = (const int*)d_in[26];
  const int* qseq    = (const int*)d_in[27];
  const int* cseq    = (const int*)d_in[28];
  const int* mseq    = (const int*)d_in[29];

  unsigned* wsU = (unsigned*)d_ws;
  float* yout = (float*)d_out;

  gikt_pack<<<(TOTAL_U + 255) / 256, 256, 0, stream>>>(Wih1, Whh1, Wih2, Whh2, Wagg, Wlast, Wqry, wsU);
  gikt_main<<<BB, T, 0, stream>>>(embQ, embC, embR, bih1, bhh1, bih2, bhh2, bagg, blast, bqry,
                                  wk, h1i, h2i, qnbr, cnbr, q2c, qseq, cseq, mseq, wsU, yout);
}

// Round 7
// 546.184 us; speedup vs baseline: 3.2364x; 1.1724x over previous
//
#include <hip/hip_runtime.h>
#include <math.h>

#define D    128
#define QN   4
#define CN   4
#define MAXC 4
#define BB   128
#define SS   64
#define RK   10
#define T    768   // 12 waves

// ---- packed-fp16 weight workspace layout (uint32 units; each uint = 2 half) ----
#define UOFF_IH1A 0        // cols 0..127 of W_ih1, chunked NT=768 K=8 (streamed) -> 24576
#define UOFF_IH1B 24576    // cols 128..255 of W_ih1: [e2l][384] -> 24576
#define UOFF_HH1  49152    // chunked NT=768 K=8 (streamed) -> 24576
#define UOFF_IH2  73728    // chunked NT=768 K=8 (register-pinned, asm) -> 24576
#define UOFF_HH2  98304    // chunked NT=768 K=8 (register-pinned, asm) -> 24576
#define UOFF_QRY  122880   // [k][128] uint4, K=16 -> 8192
#define UOFF_A0   131072   // [e2g][2][128] -> 8192
#define UOFF_A1   139264   // -> 8192
#define UOFF_LS   147456   // -> 8192
#define TOTAL_U   155648

typedef _Float16 h2_t __attribute__((ext_vector_type(2)));
union U32H2 { unsigned u; h2_t h; unsigned short s2[2]; };

__device__ __forceinline__ unsigned h16f(float x){
  U32H2 c; c.h[0] = (_Float16)x; c.h[1] = (_Float16)0.f;
  return (unsigned)c.s2[0];
}
__device__ __forceinline__ unsigned packh2(float a, float b){
  U32H2 c; c.h[0] = (_Float16)a; c.h[1] = (_Float16)b;
  return c.u;
}
__device__ __forceinline__ float dot2(unsigned w, unsigned x, float acc){
  U32H2 a; a.u = w; U32H2 b; b.u = x;
  return __builtin_amdgcn_fdot2(a.h, b.h, acc, false);
}
__device__ __forceinline__ float hlo(unsigned u){ U32H2 a; a.u=u; return (float)a.h[0]; }
__device__ __forceinline__ float hhi(unsigned u){ U32H2 a; a.u=u; return (float)a.h[1]; }

__device__ __forceinline__ float fsig(float x){ return 1.f/(1.f + __expf(-x)); }
__device__ __forceinline__ float ftanh(float x){
  float xc = fminf(fmaxf(x, -30.f), 30.f);
  float e = __expf(2.f*xc);
  return (e - 1.f)/(e + 1.f);
}

#define FD4(w4, x4, acc) { \
  acc = dot2((w4).x, (x4).x, acc); acc = dot2((w4).y, (x4).y, acc); \
  acc = dot2((w4).z, (x4).z, acc); acc = dot2((w4).w, (x4).w, acc); }

// anti-rematerialization pin: makes the loaded value opaque so the compiler
// cannot sink the load back into the loop (round-6 failure: VGPR_Count=84)
#define KEEP4(v) asm volatile("" : "+v"((v).x), "+v"((v).y), "+v"((v).z), "+v"((v).w))

__global__ void gikt_pack(const float* __restrict__ Wih1,
                          const float* __restrict__ Whh1,
                          const float* __restrict__ Wih2,
                          const float* __restrict__ Whh2,
                          const float* __restrict__ Wagg,
                          const float* __restrict__ Wlast,
                          const float* __restrict__ Wqry,
                          unsigned* __restrict__ wsU)
{
  int i = blockIdx.x * blockDim.x + threadIdx.x;
  if (i >= TOTAL_U) return;
  const float* src = nullptr; int row = 0, e2 = 0, stride = 0;
  int j = i;
  if (j < 24576) {               // ih1a
    int c = j & 3, i4 = j >> 2, k = i4 / 768, t = i4 - k * 768, r = t >> 1, hf = t & 1;
    e2 = hf * 32 + k * 4 + c; row = r; src = Wih1; stride = 256;
  } else if ((j -= 24576) < 24576) {   // ih1b
    e2 = 64 + (j / 384); row = j % 384; src = Wih1; stride = 256;
  } else if ((j -= 24576) < 24576) {   // hh1
    int c = j & 3, i4 = j >> 2, k = i4 / 768, t = i4 - k * 768, r = t >> 1, hf = t & 1;
    e2 = hf * 32 + k * 4 + c; row = r; src = Whh1; stride = 128;
  } else if ((j -= 24576) < 24576) {   // ih2
    int c = j & 3, i4 = j >> 2, k = i4 / 768, t = i4 - k * 768, r = t >> 1, hf = t & 1;
    e2 = hf * 32 + k * 4 + c; row = r; src = Wih2; stride = 128;
  } else if ((j -= 24576) < 24576) {   // hh2
    int c = j & 3, i4 = j >> 2, k = i4 / 768, t = i4 - k * 768, r = t >> 1, hf = t & 1;
    e2 = hf * 32 + k * 4 + c; row = r; src = Whh2; stride = 128;
  } else if ((j -= 24576) < 8192) {    // qry
    int c = j & 3, i4 = j >> 2, k = i4 >> 7, r = i4 & 127;
    e2 = k * 4 + c; row = r; src = Wqry; stride = 128;
  } else if ((j -= 8192) < 8192) {     // a0
    int r = j & 127, p = (j >> 7) & 1, e2g = j >> 8;
    e2 = 2 * e2g + p; row = r; src = Wagg; stride = 128;
  } else if ((j -= 8192) < 8192) {     // a1
    int r = j & 127, p = (j >> 7) & 1, e2g = j >> 8;
    e2 = 2 * e2g + p; row = r; src = Wagg + 128 * 128; stride = 128;
  } else {                              // ls
    j -= 8192;
    int r = j & 127, p = (j >> 7) & 1, e2g = j >> 8;
    e2 = 2 * e2g + p; row = r; src = Wlast; stride = 128;
  }
  float lo = src[row * stride + 2 * e2];
  float hi = src[row * stride + 2 * e2 + 1];
  wsU[i] = h16f(lo) | (h16f(hi) << 16);
}

__device__ __forceinline__ float2 gru_nl2(float2 gr, float2 gz, float2 gn,
                                          float2 hr, float2 hz, float2 hn,
                                          float2 hold){
  float2 out;
  {
    float rg = fsig(gr.x + hr.x);
    float zg = fsig(gz.x + hz.x);
    float ng = ftanh(gn.x + rg*hn.x);
    out.x = (1.f-zg)*ng + zg*hold.x;
  }
  {
    float rg = fsig(gr.y + hr.y);
    float zg = fsig(gz.y + hz.y);
    float ng = ftanh(gn.y + rg*hn.y);
    out.y = (1.f-zg)*ng + zg*hold.y;
  }
  return out;
}

__launch_bounds__(T, 1)
__global__ void gikt_main(
    const float* __restrict__ embQ,
    const float* __restrict__ embC,
    const float* __restrict__ embR,
    const float* __restrict__ b_ih1,
    const float* __restrict__ b_hh1,
    const float* __restrict__ b_ih2,
    const float* __restrict__ b_hh2,
    const float* __restrict__ b_agg,
    const float* __restrict__ b_last,
    const float* __restrict__ b_query,
    const float* __restrict__ w_k,
    const float* __restrict__ h1i,
    const float* __restrict__ h2i,
    const int* __restrict__ qnbr,
    const int* __restrict__ cnbr,
    const int* __restrict__ q2c,
    const int* __restrict__ qseq,
    const int* __restrict__ cseq,
    const int* __restrict__ mseq,
    const unsigned* __restrict__ wsU,
    float* __restrict__ y)
{
  const int b   = blockIdx.x;
  const int tid = threadIdx.x;
  const int r2  = tid >> 1, hf = tid & 1;

  __shared__ unsigned aggL[3 * 8192];          // a0|a1|ls; phase0 alias: Gram
  __shared__ __align__(16) float hist[SS][132];// state history fp32 (row0 = zero)
  __shared__ float gicorr[2][384];
  __shared__ int   idxk[SS][RK];
  __shared__ float kwh[SS];
  __shared__ __align__(16) float a_[5][D];
  __shared__ __align__(16) float gi1[3*D];
  __shared__ __align__(16) float gh1[3*D];
  __shared__ __align__(16) float gi2[3*D];
  __shared__ __align__(16) float gh2[3*D];
  __shared__ __align__(16) float h1fp[2][D];
  __shared__ __align__(16) float g2fp[2][D];
  __shared__ __align__(16) float h2ifp[D];
  __shared__ __align__(16) float qcs[2][D];
  __shared__ float kevec[D];
  __shared__ __align__(16) unsigned mPu[5][64];
  __shared__ __align__(16) unsigned vPu[64];
  __shared__ __align__(16) unsigned m1Pu[64];
  __shared__ __align__(16) unsigned xvPu[64];
  __shared__ __align__(16) unsigned h1Pu[64];
  __shared__ __align__(16) unsigned g2Pu[64];
  __shared__ __align__(16) unsigned h2iPu[64];
  __shared__ int   sq[SS], scc[SS], smk[SS];
  __shared__ int   nn1[SS][QN], nn2[SS][QN*CN], cc2[SS][MAXC];
  __shared__ float red[12];
  __shared__ float ogv[16], kwv[16];

  float (*G)[65] = (float(*)[65])aggL;

  // ---- pinned GRU2 weights: 16 uint4 = 64 VGPR, pinned FOR REAL via asm ----
  uint4 pwi[8], pwh[8];
  {
    const uint4* Pi = (const uint4*)(wsU + UOFF_IH2);
    const uint4* Ph = (const uint4*)(wsU + UOFF_HH2);
    #pragma unroll
    for (int k = 0; k < 8; ++k) { pwi[k] = Pi[k*768 + tid]; pwh[k] = Ph[k*768 + tid]; }
    #pragma unroll
    for (int k = 0; k < 8; ++k) { KEEP4(pwi[k]); KEEP4(pwh[k]); }
  }

  // ---- phase 0a: sequences ----
  for (int i = tid; i < SS; i += T) { sq[i]=qseq[b*SS+i]; scc[i]=cseq[b*SS+i]; smk[i]=mseq[b*SS+i]; }
  __syncthreads();

  // ---- phase 0b: E rows into hist; 1-hop indices ----
  for (int i = tid; i < SS*32; i += T) {
    int s = i >> 5, e4 = i & 31;
    float4 v = ((const float4*)(embQ + sq[s]*D))[e4];
    ((float4*)hist[s])[e4] = v;
  }
  for (int i = tid; i < (SS-1)*QN; i += T)   { int t = i>>2, j = i&3; nn1[t][j] = qnbr[sq[t]*QN + j]; }
  for (int i = tid; i < (SS-1)*MAXC; i += T) { int t = i>>2, j = i&3; cc2[t][j] = q2c[sq[t+1]*MAXC + j]; }
  __syncthreads();

  // ---- phase 0c: Gram (fp32, float4), 2-hop indices, gicorr ----
  for (int p = tid; p < SS*SS; p += T) {
    int tq = p >> 6, s = p & 63;
    if (tq >= RK+2 && s < tq-1) {
      const float4* ra = (const float4*)hist[tq];
      const float4* rb = (const float4*)hist[s];
      float acc = 0.f;
      #pragma unroll 8
      for (int d4 = 0; d4 < 32; ++d4) {
        float4 xa = ra[d4], xb = rb[d4];
        acc += xa.x*xb.x + xa.y*xb.y + xa.z*xb.z + xa.w*xb.w;
      }
      G[tq-(RK+2)][s] = acc;
    }
  }
  for (int i = tid; i < (SS-1)*QN*CN; i += T) {
    int t = i>>4, j = (i>>2)&3, l = i&3;
    nn2[t][j*CN+l] = cnbr[nn1[t][j]*CN + l];
  }
  {
    const int c = (tid >= 384) ? 1 : 0, r = tid - (c ? 384 : 0);
    const float2* er2 = (const float2*)(embR + c*D);
    float acc = 0.f;
    #pragma unroll 4
    for (int e2l = 0; e2l < 64; ++e2l) {
      unsigned u = wsU[UOFF_IH1B + e2l*384 + r];
      float2 x = er2[e2l];
      acc += hlo(u)*x.x + hhi(u)*x.y;
    }
    gicorr[c][r] = acc;
  }
  __syncthreads();

  // ---- phase 0d: stable top-k (ties -> lowest index, = jax.lax.top_k) ----
  if (tid < 52) {
    int t = RK + 1 + tid;
    for (int k = 0; k < RK; ++k) {
      float best = -INFINITY; int bi = 0;
      for (int s = 0; s < t; ++s) { float v = G[tid][s]; if (v > best) { best = v; bi = s; } }
      idxk[t][k] = bi;
      G[tid][bi] = -INFINITY;
    }
  }
  __syncthreads();

  // ---- phase 0e: agg weights into LDS; state init; kw(zero-state) ----
  for (int i = tid; i < 3*8192; i += T) aggL[i] = wsU[UOFF_A0 + i];
  if (tid < 64) {
    float a0 = h1i[b*D+2*tid], a1 = h1i[b*D+2*tid+1];
    h1Pu[tid] = packh2(a0, a1);
    ((float2*)h1fp[1])[tid] = make_float2(a0, a1);
    float c0 = h2i[b*D+2*tid], c1 = h2i[b*D+2*tid+1];
    h2iPu[tid] = packh2(c0, c1);
    ((float2*)h2ifp)[tid] = make_float2(c0, c1);
    g2Pu[tid] = 0;
  }
  if (tid < D) hist[0][tid] = 0.f;
  if (tid == 0) y[b*SS + 1] = 0.f;   // never written by reference
  {
    float p0 = (tid < D) ? w_k[tid]*ftanh(b_query[tid]) : 0.f;
    #pragma unroll
    for (int off = 32; off; off >>= 1) p0 += __shfl_down(p0, off);
    if ((tid & 63) == 0) red[tid >> 6] = p0;
  }
  __syncthreads();
  if (tid == 0) kwh[0] = red[0]+red[1];
  __syncthreads();

  const uint4* Wi1 = (const uint4*)(wsU + UOFF_IH1A);
  const uint4* Wh1 = (const uint4*)(wsU + UOFF_HH1);
  const uint4* Wq4 = (const uint4*)(wsU + UOFF_QRY);

  // ---- cross-step gather prefetch registers (5 floats, live across iterations) ----
  float pf0 = 0.f, pf1 = 0.f, pf2 = 0.f, pf3 = 0.f, pf4 = 0.f;

#define PREFETCH(tt) {                                                        \
    const int d_ = tid & 127, grp_ = tid >> 7;                                \
    const bool m2_ = (smk[tt] != 0);                                          \
    if (grp_ == 0) {                                                          \
      pf0 = embQ[sq[tt]*D + d_];                                              \
      if (m2_) { pf1 = embC[nn1[tt][0]*D+d_]; pf2 = embC[nn1[tt][1]*D+d_];    \
                 pf3 = embC[nn1[tt][2]*D+d_]; pf4 = embC[nn1[tt][3]*D+d_]; }  \
    } else if (grp_ <= 4) {                                                   \
      if (m2_) { const int j_ = grp_ - 1;                                     \
        pf0 = embC[nn1[tt][j_]*D + d_];                                       \
        pf1 = embQ[nn2[tt][j_*CN+0]*D+d_]; pf2 = embQ[nn2[tt][j_*CN+1]*D+d_]; \
        pf3 = embQ[nn2[tt][j_*CN+2]*D+d_]; pf4 = embQ[nn2[tt][j_*CN+3]*D+d_];}\
    } else {                                                                  \
      pf0 = embQ[sq[(tt)+1]*D + d_];                                          \
      pf1 = embC[cc2[tt][0]*D+d_]; pf2 = embC[cc2[tt][1]*D+d_];               \
      pf3 = embC[cc2[tt][2]*D+d_]; pf4 = embC[cc2[tt][3]*D+d_];               \
    } }

  PREFETCH(0);

  // ==== time loop: step t runs GRU(t); g2(t-1) finalizes in P1; predict(t-1) overlapped ====
  for (int t = 0; t < SS-1; ++t) {
    const int tp = t - 1;
    const bool msk = (smk[t] != 0);

    // ---- P1: wave0 finalizes g2(t-1); consume prefetch into LDS; issue prefetch(t+1) ----
    if (tid < 64 && t >= 1) {
      const int l = tid;
      const float* ph2 = (t <= 2) ? h2ifp : g2fp[t & 1];
      float2 hold = ((const float2*)ph2)[l];
      float2 gv = gru_nl2(((const float2*)gi2)[l], ((const float2*)(gi2+128))[l], ((const float2*)(gi2+256))[l],
                          ((const float2*)gh2)[l], ((const float2*)(gh2+128))[l], ((const float2*)(gh2+256))[l],
                          hold);
      ((float2*)g2fp[(t+1)&1])[l] = gv;
      g2Pu[l] = packh2(gv.x, gv.y);
      if (t >= 2) { hist[t-1][2*l] = gv.x; hist[t-1][2*l+1] = gv.y; }
    }
    {
      const int d = tid & 127, grp = tid >> 7;
      if (msk) {
        if (grp <= 4) ((_Float16*)mPu[grp])[d] = (_Float16)(pf0 + 0.25f*(pf1+pf2+pf3+pf4));
        else          qcs[t & 1][d] = pf0+pf1+pf2+pf3+pf4;
      } else {
        if (grp == 0)      ((_Float16*)xvPu)[d] = (_Float16)pf0;   // xv = e0 directly
        else if (grp == 5) qcs[t & 1][d] = pf0+pf1+pf2+pf3+pf4;
      }
    }
    if (t + 1 < SS-1) PREFETCH(t+1);
    __syncthreads();

    if (msk) {
      // ---- P2: agg1 (0..255) | og-prev (256..431) | qry (512..767, 2thr/row) ----
      if (tid < 128) {             // a0 = tanh(A0 @ m0 + b)
        const int r = tid;
        const unsigned* A = aggL;
        const uint2* x2p = (const uint2*)mPu[0];
        float acc0 = b_agg[r], acc1 = 0.f;
        #pragma unroll
        for (int e2g = 0; e2g < 32; e2g += 2) {
          unsigned u00 = A[e2g*256 + r],     u01 = A[e2g*256 + 128 + r];
          uint2 x0 = x2p[e2g];
          acc0 = dot2(u00, x0.x, acc0); acc0 = dot2(u01, x0.y, acc0);
          unsigned u10 = A[(e2g+1)*256 + r], u11 = A[(e2g+1)*256 + 128 + r];
          uint2 x1 = x2p[e2g+1];
          acc1 = dot2(u10, x1.x, acc1); acc1 = dot2(u11, x1.y, acc1);
        }
        a_[0][r] = ftanh(acc0 + acc1);
      } else if (tid < 256) {      // a1..a4 share the A1 row read (4 acc chains)
        const int r = tid - 128;
        const unsigned* A = aggL + 8192;
        const uint2* x1p = (const uint2*)mPu[1];
        const uint2* x2p = (const uint2*)mPu[2];
        const uint2* x3p = (const uint2*)mPu[3];
        const uint2* x4p = (const uint2*)mPu[4];
        float bb = b_agg[D + r];
        float c1 = 0.f, c2 = 0.f, c3 = 0.f, c4 = 0.f;
        #pragma unroll
        for (int e2g = 0; e2g < 32; ++e2g) {
          unsigned u0 = A[e2g*256 + r], u1 = A[e2g*256 + 128 + r];
          uint2 v1 = x1p[e2g]; c1 = dot2(u0, v1.x, c1); c1 = dot2(u1, v1.y, c1);
          uint2 v2 = x2p[e2g]; c2 = dot2(u0, v2.x, c2); c2 = dot2(u1, v2.y, c2);
          uint2 v3 = x3p[e2g]; c3 = dot2(u0, v3.x, c3); c3 = dot2(u1, v3.y, c3);
          uint2 v4 = x4p[e2g]; c4 = dot2(u0, v4.x, c4); c4 = dot2(u1, v4.y, c4);
        }
        a_[1][r] = ftanh(bb + c1); a_[2][r] = ftanh(bb + c2);
        a_[3][r] = ftanh(bb + c3); a_[4][r] = ftanh(bb + c4);
      } else if (tid < 432 && t >= 1) {   // og dots for predict(t-1)
        const int g = (tid - 256) >> 4, lane = tid & 15;
        const int ne = (tp < RK ? tp : RK) + 1;
        if (g < ne) {
          const float* row;
          if (g == 0) row = g2fp[(t+1)&1];
          else {
            int s = (tp <= RK) ? (g-1) : idxk[tp][g-1];
            row = hist[s];
            if (lane == 0) kwv[g] = kwh[s];
          }
          const float* qp = qcs[tp & 1];
          float part = 0.f;
          #pragma unroll
          for (int k = 0; k < 8; ++k) { int d = lane + (k<<4); part += qp[d]*row[d]; }
          part += __shfl_xor(part, 8, 16);
          part += __shfl_xor(part, 4, 16);
          part += __shfl_xor(part, 2, 16);
          part += __shfl_xor(part, 1, 16);
          if (lane == 0) ogv[g] = part;
        }
      } else if (tid >= 512) {     // qry on g2(t-1), 2 thr/row
        const int rq = (tid - 512) >> 1, hq = tid & 1;
        const uint4* g2p4 = (const uint4*)g2Pu;
        float a0 = hq ? 0.f : b_query[rq], a1 = 0.f;
        #pragma unroll
        for (int k = hq*8; k < hq*8+8; k += 2) {
          uint4 u0 = Wq4[k*128 + rq];     uint4 x0 = g2p4[k];   FD4(u0, x0, a0);
          uint4 u1 = Wq4[(k+1)*128 + rq]; uint4 x1 = g2p4[k+1]; FD4(u1, x1, a1);
        }
        float acc = a0 + a1; acc += __shfl_xor(acc, 1);
        if (!hq) kevec[rq] = ftanh(acc) * w_k[rq];
      }
      __syncthreads();

      // ---- P3: agg2 (0..255) | kw-reduce (512..575) ----
      if (tid < 256) {
        const int l = tid & 63;
        float v0 = a_[0][2*l]   + 0.25f*(a_[1][2*l]  +a_[2][2*l]  +a_[3][2*l]  +a_[4][2*l]);
        float v1 = a_[0][2*l+1] + 0.25f*(a_[1][2*l+1]+a_[2][2*l+1]+a_[3][2*l+1]+a_[4][2*l+1]);
        vPu[l] = packh2(v0, v1);
        const int r = tid >> 1, h = tid & 1;
        const uint2* x2p = (const uint2*)vPu;
        float acc0 = h ? 0.f : b_agg[r], acc1 = 0.f;
        #pragma unroll
        for (int e2g = h*16; e2g < h*16+16; e2g += 2) {
          unsigned u00 = aggL[e2g*256 + r],     u01 = aggL[e2g*256 + 128 + r];
          uint2 x0 = x2p[e2g];
          acc0 = dot2(u00, x0.x, acc0); acc0 = dot2(u01, x0.y, acc0);
          unsigned u10 = aggL[(e2g+1)*256 + r], u11 = aggL[(e2g+1)*256 + 128 + r];
          uint2 x1 = x2p[e2g+1];
          acc1 = dot2(u10, x1.x, acc1); acc1 = dot2(u11, x1.y, acc1);
        }
        float acc = acc0 + acc1; acc += __shfl_xor(acc, 1);
        if (!h) ((_Float16*)m1Pu)[r] = (_Float16)ftanh(acc);
      } else if (tid >= 512 && tid < 576 && t >= 1) {
        const int lane = tid & 63;
        float v = kevec[lane] + kevec[lane + 64];
        #pragma unroll
        for (int off = 32; off; off >>= 1) v += __shfl_down(v, off);
        if (lane == 0) { kwv[0] = v; if (tp >= 1) kwh[tp] = v; }
      }
      __syncthreads();

      // ---- P4: ls -> xvPu (0..255) | y-write prev (tid 256) ----
      if (tid < 256) {
        const int r = tid >> 1, h = tid & 1;
        const unsigned* A = aggL + 16384;
        const uint2* x2p = (const uint2*)m1Pu;
        float acc0 = h ? 0.f : b_last[r], acc1 = 0.f;
        #pragma unroll
        for (int e2g = h*16; e2g < h*16+16; e2g += 2) {
          unsigned u00 = A[e2g*256 + r],     u01 = A[e2g*256 + 128 + r];
          uint2 x0 = x2p[e2g];
          acc0 = dot2(u00, x0.x, acc0); acc0 = dot2(u01, x0.y, acc0);
          unsigned u10 = A[(e2g+1)*256 + r], u11 = A[(e2g+1)*256 + 128 + r];
          uint2 x1 = x2p[e2g+1];
          acc1 = dot2(u10, x1.x, acc1); acc1 = dot2(u11, x1.y, acc1);
        }
        float acc = acc0 + acc1; acc += __shfl_xor(acc, 1);
        if (!h) ((_Float16*)xvPu)[r] = (_Float16)ftanh(acc);
      } else if (tid == 256 && t >= 1) {
        const int ne = (tp < RK ? tp : RK) + 1;
        float mx = kwv[0];
        for (int i2 = 1; i2 < ne; ++i2) mx = fmaxf(mx, kwv[i2]);
        float den = 0.f, num = 0.f;
        for (int i2 = 0; i2 < ne; ++i2) { float e_ = __expf(kwv[i2]-mx); den += e_; num += e_*ogv[i2]; }
        y[b*SS + ((tp==0) ? 0 : (tp+1))] = fsig(num/den);
      }
      __syncthreads();

      // ---- P5: GRU1 (streamed weights, 2thr/row) ----
      {
        const uint4* xvp4 = (const uint4*)xvPu;
        const uint4* h1p4 = (const uint4*)h1Pu;
        float ai0 = hf ? 0.f : (b_ih1[r2] + gicorr[scc[t]][r2]), ai1 = 0.f;
        float ah0 = hf ? 0.f : b_hh1[r2], ah1 = 0.f;
        #pragma unroll
        for (int k = 0; k < 8; k += 2) {
          uint4 w0 = Wi1[k*768 + tid], w1 = Wi1[(k+1)*768 + tid];
          uint4 xa = xvp4[hf*8+k], xb = xvp4[hf*8+k+1];
          FD4(w0, xa, ai0); FD4(w1, xb, ai1);
          uint4 v0 = Wh1[k*768 + tid], v1 = Wh1[(k+1)*768 + tid];
          uint4 ya = h1p4[hf*8+k], yb = h1p4[hf*8+k+1];
          FD4(v0, ya, ah0); FD4(v1, yb, ah1);
        }
        float acc_i = ai0 + ai1; acc_i += __shfl_xor(acc_i, 1);
        float acc_h = ah0 + ah1; acc_h += __shfl_xor(acc_h, 1);
        if (!hf) { gi1[r2] = acc_i; gh1[r2] = acc_h; }
      }
      __syncthreads();
    } else {
      // ---- P2'' (mask==0): og + qry pre-work, then GRU1 on all threads ----
      if (tid >= 256 && tid < 432 && t >= 1) {
        const int g = (tid - 256) >> 4, lane = tid & 15;
        const int ne = (tp < RK ? tp : RK) + 1;
        if (g < ne) {
          const float* row;
          if (g == 0) row = g2fp[(t+1)&1];
          else {
            int s = (tp <= RK) ? (g-1) : idxk[tp][g-1];
            row = hist[s];
            if (lane == 0) kwv[g] = kwh[s];
          }
          const float* qp = qcs[tp & 1];
          float part = 0.f;
          #pragma unroll
          for (int k = 0; k < 8; ++k) { int d = lane + (k<<4); part += qp[d]*row[d]; }
          part += __shfl_xor(part, 8, 16);
          part += __shfl_xor(part, 4, 16);
          part += __shfl_xor(part, 2, 16);
          part += __shfl_xor(part, 1, 16);
          if (lane == 0) ogv[g] = part;
        }
      } else if (tid >= 512) {
        const int rq = (tid - 512) >> 1, hq = tid & 1;
        const uint4* g2p4 = (const uint4*)g2Pu;
        float a0 = hq ? 0.f : b_query[rq], a1 = 0.f;
        #pragma unroll
        for (int k = hq*8; k < hq*8+8; k += 2) {
          uint4 u0 = Wq4[k*128 + rq];     uint4 x0 = g2p4[k];   FD4(u0, x0, a0);
          uint4 u1 = Wq4[(k+1)*128 + rq]; uint4 x1 = g2p4[k+1]; FD4(u1, x1, a1);
        }
        float acc = a0 + a1; acc += __shfl_xor(acc, 1);
        if (!hq) kevec[rq] = ftanh(acc) * w_k[rq];
      }
      {
        const uint4* xvp4 = (const uint4*)xvPu;
        const uint4* h1p4 = (const uint4*)h1Pu;
        float ai0 = hf ? 0.f : (b_ih1[r2] + gicorr[scc[t]][r2]), ai1 = 0.f;
        float ah0 = hf ? 0.f : b_hh1[r2], ah1 = 0.f;
        #pragma unroll
        for (int k = 0; k < 8; k += 2) {
          uint4 w0 = Wi1[k*768 + tid], w1 = Wi1[(k+1)*768 + tid];
          uint4 xa = xvp4[hf*8+k], xb = xvp4[hf*8+k+1];
          FD4(w0, xa, ai0); FD4(w1, xb, ai1);
          uint4 v0 = Wh1[k*768 + tid], v1 = Wh1[(k+1)*768 + tid];
          uint4 ya = h1p4[hf*8+k], yb = h1p4[hf*8+k+1];
          FD4(v0, ya, ah0); FD4(v1, yb, ah1);
        }
        float acc_i = ai0 + ai1; acc_i += __shfl_xor(acc_i, 1);
        float acc_h = ah0 + ah1; acc_h += __shfl_xor(acc_h, 1);
        if (!hf) { gi1[r2] = acc_i; gh1[r2] = acc_h; }
      }
      __syncthreads();
    }

    // ---- P6: [mask==0: wave0 kw+y] ; redundant GRU1-nl ; GRU2 (pinned) ----
    if (!msk && t >= 1 && tid < 64) {
      float v = kevec[tid] + kevec[tid + 64];
      #pragma unroll
      for (int off = 32; off; off >>= 1) v += __shfl_down(v, off);
      if (tid == 0) {
        if (tp >= 1) kwh[tp] = v;
        const int ne = (tp < RK ? tp : RK) + 1;
        float mx = v;
        for (int i2 = 1; i2 < ne; ++i2) mx = fmaxf(mx, kwv[i2]);
        float den = __expf(v - mx), num = den*ogv[0];
        for (int i2 = 1; i2 < ne; ++i2) { float e_ = __expf(kwv[i2]-mx); den += e_; num += e_*ogv[i2]; }
        y[b*SS + ((tp==0) ? 0 : (tp+1))] = fsig(num/den);
      }
    }
    {
      const int l = tid & 63;
      float2 hold = ((const float2*)h1fp[(t+1)&1])[l];
      float2 hn = gru_nl2(((const float2*)gi1)[l], ((const float2*)(gi1+128))[l], ((const float2*)(gi1+256))[l],
                          ((const float2*)gh1)[l], ((const float2*)(gh1+128))[l], ((const float2*)(gh1+256))[l],
                          hold);
      ((float2*)h1fp[t&1])[l] = hn;
      h1Pu[l] = packh2(hn.x, hn.y);
    }
    {
      const uint4* xh1 = (const uint4*)h1Pu;
      const uint4* xh2 = (t <= 1) ? (const uint4*)h2iPu : (const uint4*)g2Pu;
      float ai0 = hf ? 0.f : b_ih2[r2], ai1 = 0.f;
      float ah0 = hf ? 0.f : b_hh2[r2], ah1 = 0.f;
      #pragma unroll
      for (int k = 0; k < 8; k += 2) {
        uint4 xa = xh1[hf*8+k], xb = xh1[hf*8+k+1];
        FD4(pwi[k], xa, ai0); FD4(pwi[k+1], xb, ai1);
        uint4 ya = xh2[hf*8+k], yb = xh2[hf*8+k+1];
        FD4(pwh[k], ya, ah0); FD4(pwh[k+1], yb, ah1);
      }
      float acc_i = ai0 + ai1; acc_i += __shfl_xor(acc_i, 1);
      float acc_h = ah0 + ah1; acc_h += __shfl_xor(acc_h, 1);
      if (!hf) { gi2[r2] = acc_i; gh2[r2] = acc_h; }
    }
    __syncthreads();
  }

  // ==== epilogue: finalize g2(62), predict(62) -> y[63] ====
  if (tid < 64) {
    const int l = tid;
    const float* ph2 = g2fp[1];
    float2 hold = ((const float2*)ph2)[l];
    float2 gv = gru_nl2(((const float2*)gi2)[l], ((const float2*)(gi2+128))[l], ((const float2*)(gi2+256))[l],
                        ((const float2*)gh2)[l], ((const float2*)(gh2+128))[l], ((const float2*)(gh2+256))[l],
                        hold);
    ((float2*)g2fp[0])[l] = gv;
    g2Pu[l] = packh2(gv.x, gv.y);
  }
  __syncthreads();
  if (tid < 128) {
    const int r = tid;
    const uint4* g2p4 = (const uint4*)g2Pu;
    float a0 = b_query[r], a1 = 0.f;
    #pragma unroll
    for (int k = 0; k < 16; k += 2) {
      uint4 u0 = Wq4[k*128 + r];     uint4 x0 = g2p4[k];   FD4(u0, x0, a0);
      uint4 u1 = Wq4[(k+1)*128 + r]; uint4 x1 = g2p4[k+1]; FD4(u1, x1, a1);
    }
    kevec[r] = ftanh(a0 + a1) * w_k[r];
  }
  __syncthreads();
  {
    const int tp = SS - 2;   // 62
    if (tid < 176) {
      const int g = tid >> 4, lane = tid & 15;
      const int ne = RK + 1;
      if (g < ne) {
        const float* row;
        if (g == 0) row = g2fp[0];
        else {
          int s = idxk[tp][g-1];
          row = hist[s];
          if (lane == 0) kwv[g] = kwh[s];
        }
        const float* qp = qcs[tp & 1];
        float part = 0.f;
        #pragma unroll
        for (int k = 0; k < 8; ++k) { int d = lane + (k<<4); part += qp[d]*row[d]; }
        part += __shfl_xor(part, 8, 16);
        part += __shfl_xor(part, 4, 16);
        part += __shfl_xor(part, 2, 16);
        part += __shfl_xor(part, 1, 16);
        if (lane == 0) ogv[g] = part;
      }
    } else if (tid >= 256 && tid < 320) {
      const int lane = tid & 63;
      float v = kevec[lane] + kevec[lane + 64];
      #pragma unroll
      for (int off = 32; off; off >>= 1) v += __shfl_down(v, off);
      if (lane == 0) kwv[0] = v;
    }
  }
  __syncthreads();
  if (tid == 0) {
    const int ne = RK + 1;
    float mx = kwv[0];
    for (int i2 = 1; i2 < ne; ++i2) mx = fmaxf(mx, kwv[i2]);
    float den = 0.f, num = 0.f;
    for (int i2 = 0; i2 < ne; ++i2) { float e_ = __expf(kwv[i2]-mx); den += e_; num += e_*ogv[i2]; }
    y[b*SS + SS - 1] = fsig(num/den);
  }
}

extern "C" void kernel_launch(void* const* d_in, const int* in_sizes, int n_in,
                              void* d_out, int out_size, void* d_ws, size_t ws_size,
                              hipStream_t stream)
{
  (void)in_sizes; (void)n_in; (void)out_size; (void)ws_size;

  const float* embQ  = (const float*)d_in[0];
  const float* embC  = (const float*)d_in[1];
  const float* embR  = (const float*)d_in[2];
  const float* Wih1  = (const float*)d_in[3];
  const float* Whh1  = (const float*)d_in[4];
  const float* bih1  = (const float*)d_in[5];
  const float* bhh1  = (const float*)d_in[6];
  const float* Wih2  = (const float*)d_in[7];
  const float* Whh2  = (const float*)d_in[8];
  const float* bih2  = (const float*)d_in[9];
  const float* bhh2  = (const float*)d_in[10];
  const float* Wagg  = (const float*)d_in[11];
  const float* bagg  = (const float*)d_in[12];
  const float* Wlast = (const float*)d_in[13];
  const float* blast = (const float*)d_in[14];
  const float* Wqry  = (const float*)d_in[15];
  const float* bqry  = (const float*)d_in[16];
  // d_in[17] W_key, [18] b_key, [19] w_q, [21] b_w cancel in the softmax -> unused
  const float* wk    = (const float*)d_in[20];
  const float* h1i   = (const float*)d_in[22];
  const float* h2i   = (const float*)d_in[23];
  const int* qnbr    = (const int*)d_in[24];
  const int* cnbr    = (const int*)d_in[25];
  const int* q2c     = (const int*)d_in[26];
  const int* qseq    = (const int*)d_in[27];
  const int* cseq    = (const int*)d_in[28];
  const int* mseq    = (const int*)d_in[29];

  unsigned* wsU = (unsigned*)d_ws;
  float* yout = (float*)d_out;

  gikt_pack<<<(TOTAL_U + 255) / 256, 256, 0, stream>>>(Wih1, Whh1, Wih2, Whh2, Wagg, Wlast, Wqry, wsU);
  gikt_main<<<BB, T, 0, stream>>>(embQ, embC, embR, bih1, bhh1, bih2, bhh2, bagg, blast, bqry,
                                  wk, h1i, h2i, qnbr, cnbr, q2c, qseq, cseq, mseq, wsU, yout);
}